// Round 3
// baseline (5839.933 us; speedup 1.0000x reference)
//
#include <hip/hip_runtime.h>
#include <hip/hip_bf16.h>

namespace {

typedef __bf16 bf16x8 __attribute__((ext_vector_type(8)));
typedef float  f32x4  __attribute__((ext_vector_type(4)));

constexpr int NTOK  = 3137;          // 1 + 16*196
constexpr int DIM   = 512;
constexpr int NH    = 8;
constexpr int DH    = 64;
constexpr int BH    = 64;            // BATCH*NH
constexpr int MROWS = 8 * NTOK;      // 25096
constexpr int MF    = 266;           // NB_FEATURES
constexpr int NSP   = 196;
constexpr int NG    = 1024;          // BH * f

constexpr float DN     = 0.35355339059327379f;  // 64^-0.25
constexpr float HDN2   = 0.0625f;               // 0.5 * 64^-0.5
constexpr float RATIO  = 0.0613139368f;         // 266^-0.5
constexpr float EPSV   = 1.0e-4f;
constexpr float QSCALE = 0.125f;                // 64^-0.5

__device__ __forceinline__ float b2f(unsigned short u) {
  union { unsigned int i; float f; } cv;
  cv.i = ((unsigned int)u) << 16;
  return cv.f;
}
__device__ __forceinline__ unsigned short f2b(float f) {
  __hip_bfloat16 h = __float2bfloat16(f);
  union { __hip_bfloat16 h; unsigned short u; } cv;
  cv.h = h;
  return cv.u;
}
__device__ __forceinline__ unsigned int pk2(float a, float b) {
  return (unsigned int)f2b(a) | ((unsigned int)f2b(b) << 16);
}

// ============ MFMA GEMM 1: qkv = x @ W_qkv, scatter bf16 q/k/v ==============
// 128x128 tile, BK=64, 4 waves (2x2 of 64x64), 16x16x32 bf16 MFMA.
__global__ __launch_bounds__(256) void k_qkv(
    const float* __restrict__ x,   // [MROWS][512]
    const float* __restrict__ w,   // [512][1536]
    unsigned short* __restrict__ qb, unsigned short* __restrict__ kb,
    unsigned short* __restrict__ vb)
{
  __shared__ alignas(16) unsigned short As[128 * 72];  // [m][k] pad 72
  __shared__ alignas(16) unsigned short Bs[128 * 72];  // [n][k] pad 72
  const int bm = blockIdx.x, bn = blockIdx.y;
  const int tid = threadIdx.x;
  const int lane = tid & 63, wid = tid >> 6;
  const int wr = wid >> 1, wc = wid & 1;
  const int row0 = bm * 128, col0 = bn * 128;
  const int l15 = lane & 15, l4 = lane >> 4;

  f32x4 acc[4][4];
  #pragma unroll
  for (int i = 0; i < 4; ++i)
    #pragma unroll
    for (int j = 0; j < 4; ++j) acc[i][j] = f32x4{0.f, 0.f, 0.f, 0.f};

  for (int kt = 0; kt < 512; kt += 64) {
    {  // stage A (fp32 -> bf16), thread: row r, 32 k's
      const int r = tid >> 1, k0 = (tid & 1) * 32;
      const int gr = row0 + r;
      if (gr < MROWS) {
        const float* src = x + (size_t)gr * 512 + kt + k0;
        #pragma unroll
        for (int cch = 0; cch < 4; ++cch) {
          const float4 f0 = *(const float4*)(src + cch * 8);
          const float4 f1 = *(const float4*)(src + cch * 8 + 4);
          uint4 u;
          u.x = pk2(f0.x, f0.y); u.y = pk2(f0.z, f0.w);
          u.z = pk2(f1.x, f1.y); u.w = pk2(f1.z, f1.w);
          *(uint4*)&As[r * 72 + k0 + cch * 8] = u;
        }
      } else {
        const uint4 z = {0, 0, 0, 0};
        #pragma unroll
        for (int cch = 0; cch < 4; ++cch) *(uint4*)&As[r * 72 + k0 + cch * 8] = z;
      }
    }
    {  // stage B transposed: Bs[n][k] = W[kt+k][col0+n]
      const int kk = tid >> 2, j0 = (tid & 3) * 32;
      const float* src = w + (size_t)(kt + kk) * 1536 + col0 + j0;
      #pragma unroll
      for (int jc = 0; jc < 32; jc += 4) {
        const float4 f = *(const float4*)(src + jc);
        Bs[(j0 + jc + 0) * 72 + kk] = f2b(f.x);
        Bs[(j0 + jc + 1) * 72 + kk] = f2b(f.y);
        Bs[(j0 + jc + 2) * 72 + kk] = f2b(f.z);
        Bs[(j0 + jc + 3) * 72 + kk] = f2b(f.w);
      }
    }
    __syncthreads();
    #pragma unroll
    for (int ks = 0; ks < 2; ++ks) {
      bf16x8 af[4], bfr[4];
      #pragma unroll
      for (int i = 0; i < 4; ++i)
        af[i] = *(const bf16x8*)&As[(wr * 64 + i * 16 + l15) * 72 + ks * 32 + l4 * 8];
      #pragma unroll
      for (int i = 0; i < 4; ++i)
        bfr[i] = *(const bf16x8*)&Bs[(wc * 64 + i * 16 + l15) * 72 + ks * 32 + l4 * 8];
      #pragma unroll
      for (int mi = 0; mi < 4; ++mi)
        #pragma unroll
        for (int ni = 0; ni < 4; ++ni)
          acc[mi][ni] = __builtin_amdgcn_mfma_f32_16x16x32_bf16(
              af[mi], bfr[ni], acc[mi][ni], 0, 0, 0);
    }
    __syncthreads();
  }
  // epilogue: scatter to q/k/v with head reshape
  #pragma unroll
  for (int mi = 0; mi < 4; ++mi) {
    #pragma unroll
    for (int r = 0; r < 4; ++r) {
      const int grow = row0 + wr * 64 + mi * 16 + l4 * 4 + r;
      if (grow < MROWS) {
        const int bb = grow / NTOK, n = grow - bb * NTOK;
        #pragma unroll
        for (int ni = 0; ni < 4; ++ni) {
          const int gc = col0 + wc * 64 + ni * 16 + l15;
          const int which = gc >> 9;
          const int col = gc & 511;
          const int hh = col >> 6, d = col & 63;
          const size_t off = (size_t)((bb * NH + hh) * NTOK + n) * DH + d;
          const float vv = acc[mi][ni][r];
          if (which == 0)      qb[off] = f2b(vv * QSCALE);
          else if (which == 1) kb[off] = f2b(vv);
          else                 vb[off] = f2b(vv);
        }
      }
    }
  }
}

// ============ MFMA GEMM 2: out = attn(bf16) @ W_out -> fp32 =================
__global__ __launch_bounds__(256) void k_out(
    const unsigned short* __restrict__ a,   // bf16 [MROWS][512]
    const float* __restrict__ w,            // fp32 [512][512]
    float* __restrict__ out)                // fp32 [MROWS][512]
{
  __shared__ alignas(16) unsigned short As[128 * 72];
  __shared__ alignas(16) unsigned short Bs[128 * 72];
  const int bm = blockIdx.x, bn = blockIdx.y;
  const int tid = threadIdx.x;
  const int lane = tid & 63, wid = tid >> 6;
  const int wr = wid >> 1, wc = wid & 1;
  const int row0 = bm * 128, col0 = bn * 128;
  const int l15 = lane & 15, l4 = lane >> 4;

  f32x4 acc[4][4];
  #pragma unroll
  for (int i = 0; i < 4; ++i)
    #pragma unroll
    for (int j = 0; j < 4; ++j) acc[i][j] = f32x4{0.f, 0.f, 0.f, 0.f};

  for (int kt = 0; kt < 512; kt += 64) {
    {  // stage A (bf16 direct copy)
      const int r = tid >> 1, k0 = (tid & 1) * 32;
      const int gr = row0 + r;
      if (gr < MROWS) {
        const unsigned short* src = a + (size_t)gr * 512 + kt + k0;
        #pragma unroll
        for (int cch = 0; cch < 4; ++cch)
          *(uint4*)&As[r * 72 + k0 + cch * 8] = *(const uint4*)(src + cch * 8);
      } else {
        const uint4 z = {0, 0, 0, 0};
        #pragma unroll
        for (int cch = 0; cch < 4; ++cch) *(uint4*)&As[r * 72 + k0 + cch * 8] = z;
      }
    }
    {  // stage B transposed
      const int kk = tid >> 2, j0 = (tid & 3) * 32;
      const float* src = w + (size_t)(kt + kk) * 512 + col0 + j0;
      #pragma unroll
      for (int jc = 0; jc < 32; jc += 4) {
        const float4 f = *(const float4*)(src + jc);
        Bs[(j0 + jc + 0) * 72 + kk] = f2b(f.x);
        Bs[(j0 + jc + 1) * 72 + kk] = f2b(f.y);
        Bs[(j0 + jc + 2) * 72 + kk] = f2b(f.z);
        Bs[(j0 + jc + 3) * 72 + kk] = f2b(f.w);
      }
    }
    __syncthreads();
    #pragma unroll
    for (int ks = 0; ks < 2; ++ks) {
      bf16x8 af[4], bfr[4];
      #pragma unroll
      for (int i = 0; i < 4; ++i)
        af[i] = *(const bf16x8*)&As[(wr * 64 + i * 16 + l15) * 72 + ks * 32 + l4 * 8];
      #pragma unroll
      for (int i = 0; i < 4; ++i)
        bfr[i] = *(const bf16x8*)&Bs[(wc * 64 + i * 16 + l15) * 72 + ks * 32 + l4 * 8];
      #pragma unroll
      for (int mi = 0; mi < 4; ++mi)
        #pragma unroll
        for (int ni = 0; ni < 4; ++ni)
          acc[mi][ni] = __builtin_amdgcn_mfma_f32_16x16x32_bf16(
              af[mi], bfr[ni], acc[mi][ni], 0, 0, 0);
    }
    __syncthreads();
  }
  #pragma unroll
  for (int mi = 0; mi < 4; ++mi) {
    #pragma unroll
    for (int r = 0; r < 4; ++r) {
      const int grow = row0 + wr * 64 + mi * 16 + l4 * 4 + r;
      if (grow < MROWS) {
        #pragma unroll
        for (int ni = 0; ni < 4; ++ni) {
          const int gc = col0 + wc * 64 + ni * 16 + l15;
          out[(size_t)grow * 512 + gc] = acc[mi][ni][r];
        }
      }
    }
  }
}

// ---------------- cls-token softmax attention (unchanged) -------------------
__global__ __launch_bounds__(256) void k_cls(
    const unsigned short* __restrict__ qb, const unsigned short* __restrict__ kb,
    const unsigned short* __restrict__ vb, unsigned short* __restrict__ attnb)
{
  __shared__ float sim[NTOK];
  __shared__ float qv[DH];
  __shared__ float sred[4], sred2[4];
  __shared__ float pbuf[4][DH];
  const int bh = blockIdx.x, tid = threadIdx.x;
  const int wv = tid >> 6, dcl = tid & 63;
  const unsigned short* ks = kb + (size_t)bh * NTOK * DH;
  const unsigned short* vs = vb + (size_t)bh * NTOK * DH;
  if (tid < DH) qv[tid] = b2f(qb[(size_t)bh * NTOK * DH + tid]);
  __syncthreads();
  float lmax = -1e30f;
  for (int j = tid; j < NTOK; j += 256) {
    const unsigned short* kr = ks + (size_t)j * DH;
    float dot = 0.f;
    #pragma unroll
    for (int d = 0; d < DH; ++d) dot += qv[d] * b2f(kr[d]);
    sim[j] = dot;
    lmax = fmaxf(lmax, dot);
  }
  #pragma unroll
  for (int off = 32; off; off >>= 1) lmax = fmaxf(lmax, __shfl_xor(lmax, off));
  if ((tid & 63) == 0) sred[wv] = lmax;
  __syncthreads();
  const float mx = fmaxf(fmaxf(sred[0], sred[1]), fmaxf(sred[2], sred[3]));
  float lsum = 0.f;
  for (int j = tid; j < NTOK; j += 256) {
    const float p = expf(sim[j] - mx);
    sim[j] = p;
    lsum += p;
  }
  #pragma unroll
  for (int off = 32; off; off >>= 1) lsum += __shfl_xor(lsum, off);
  __syncthreads();
  if ((tid & 63) == 0) sred2[wv] = lsum;
  __syncthreads();
  const float tot = sred2[0] + sred2[1] + sred2[2] + sred2[3];
  float accv = 0.f;
  for (int j = wv; j < NTOK; j += 4) accv += sim[j] * b2f(vs[(size_t)j * DH + dcl]);
  pbuf[wv][dcl] = accv;
  __syncthreads();
  if (tid < DH) {
    const float o = (pbuf[0][tid] + pbuf[1][tid] + pbuf[2][tid] + pbuf[3][tid]) / tot;
    const int bb = bh >> 3, hh = bh & 7;
    attnb[((size_t)bb * NTOK + 0) * DIM + hh * DH + tid] = f2b(o);
  }
}

// ---------------- batched global key-projection max -------------------------
__global__ __launch_bounds__(256) void k_keymax(
    const unsigned short* __restrict__ kb, const float* __restrict__ proj,
    float* __restrict__ pmax)
{
  __shared__ alignas(16) unsigned short projL[MF * 72];   // [m][d] pad 72
  __shared__ alignas(16) unsigned short kv8[8 * 64];
  __shared__ float sred[4];
  const int g = blockIdx.x, bh = g >> 4, c = g & 15;
  const int tid = threadIdx.x;
  const bool m1ok = (tid < MF - 256);
  for (int idx = tid; idx < MF * DH; idx += 256) {
    const int m = idx >> 6, d = idx & 63;
    projL[m * 72 + d] = f2b(proj[idx]);
  }
  const unsigned short* ksrc = kb + (size_t)bh * NTOK * DH;
  float lmax = -1e30f;
  for (int nb = 0; nb < 25; ++nb) {
    const int tc = (197 - nb * 8 < 8) ? (197 - nb * 8) : 8;
    __syncthreads();
    if (tid < 64) {
      const int t = tid >> 3, cc = tid & 7;
      if (t < tc) {
        const int n = nb * 8 + t;
        const int node = (n == 0) ? 0 : (1 + c * NSP + (n - 1));
        *(uint4*)&kv8[t * 64 + cc * 8] =
            *(const uint4*)(ksrc + (size_t)node * 64 + cc * 8);
      }
    }
    __syncthreads();
    float dot0[8], dot1[8];
    #pragma unroll
    for (int t = 0; t < 8; ++t) { dot0[t] = 0.f; dot1[t] = 0.f; }
    #pragma unroll
    for (int d0 = 0; d0 < 64; d0 += 8) {
      const bf16x8 p0 = *(const bf16x8*)&projL[tid * 72 + d0];
      float pf0[8], pf1[8];
      #pragma unroll
      for (int j = 0; j < 8; ++j) pf0[j] = (float)p0[j];
      if (m1ok) {
        const bf16x8 p1 = *(const bf16x8*)&projL[(256 + tid) * 72 + d0];
        #pragma unroll
        for (int j = 0; j < 8; ++j) pf1[j] = (float)p1[j];
      } else {
        #pragma unroll
        for (int j = 0; j < 8; ++j) pf1[j] = 0.f;
      }
      #pragma unroll
      for (int t = 0; t < 8; ++t) {
        const bf16x8 kc = *(const bf16x8*)&kv8[t * 64 + d0];
        #pragma unroll
        for (int j = 0; j < 8; ++j) {
          const float kf = (float)kc[j];
          dot0[t] += kf * pf0[j];
          if (m1ok) dot1[t] += kf * pf1[j];
        }
      }
    }
    #pragma unroll
    for (int t = 0; t < 8; ++t) {
      if (t < tc) {
        lmax = fmaxf(lmax, DN * dot0[t]);
        if (m1ok) lmax = fmaxf(lmax, DN * dot1[t]);
      }
    }
  }
  #pragma unroll
  for (int off = 32; off; off >>= 1) lmax = fmaxf(lmax, __shfl_xor(lmax, off));
  if ((tid & 63) == 0) sred[tid >> 6] = lmax;
  __syncthreads();
  if (tid == 0) pmax[g] = fmaxf(fmaxf(sred[0], sred[1]), fmaxf(sred[2], sred[3]));
}

__global__ __launch_bounds__(256) void k_maxred(
    const float* __restrict__ pmax, float* __restrict__ gmax)
{
  __shared__ float sred[4];
  float v = -1e30f;
  for (int i = threadIdx.x; i < NG; i += 256) v = fmaxf(v, pmax[i]);
  #pragma unroll
  for (int off = 32; off; off >>= 1) v = fmaxf(v, __shfl_xor(v, off));
  if ((threadIdx.x & 63) == 0) sred[threadIdx.x >> 6] = v;
  __syncthreads();
  if (threadIdx.x == 0)
    gmax[0] = fmaxf(fmaxf(sred[0], sred[1]), fmaxf(sred[2], sred[3]));
}

// ------- fused per-group, 8-token batched: ctx + ksum + query + output ------
__global__ __launch_bounds__(256) void k_fused(
    const unsigned short* __restrict__ qb, const unsigned short* __restrict__ kb,
    const unsigned short* __restrict__ vb, const float* __restrict__ proj,
    const float* __restrict__ gmaxp, unsigned short* __restrict__ attnb)
{
  __shared__ alignas(16) unsigned short projL[MF * 72];   // [m][d] pad 72
  __shared__ alignas(16) unsigned short kv8[8 * 64];
  __shared__ alignas(16) unsigned short vv8[8 * 64];
  __shared__ alignas(16) float prowT[MF * 12];            // [m][t] pad 12
  __shared__ float pbuf[8][4][64];
  __shared__ float diag8[8];
  __shared__ float sredA[8][4];
  __shared__ float sredD[8][4];
  const int g = blockIdx.x, bh = g >> 4, c = g & 15;
  const int bb = bh >> 3, hh = bh & 7;
  const int tid = threadIdx.x;
  const int wv = tid >> 6, dcl = tid & 63;
  const bool m1ok = (tid < MF - 256);
  const float gm = gmaxp[0];

  for (int idx = tid; idx < MF * DH; idx += 256) {
    const int m = idx >> 6, d = idx & 63;
    projL[m * 72 + d] = f2b(proj[idx]);
  }
  const unsigned short* ksrc = kb + (size_t)bh * NTOK * DH;
  const unsigned short* vsrc = vb + (size_t)bh * NTOK * DH;
  const unsigned short* qsrc = qb + (size_t)bh * NTOK * DH;

  float ctx_r[67];
  #pragma unroll
  for (int i = 0; i < 67; ++i) ctx_r[i] = 0.f;
  float ks0 = 0.f, ks1 = 0.f;

  // ================= phase A: keys -> ctx_r, ksum =================
  for (int nb = 0; nb < 25; ++nb) {
    const int tc = (197 - nb * 8 < 8) ? (197 - nb * 8) : 8;
    __syncthreads();
    if (tid < 128) {
      const int t = (tid & 63) >> 3, cc = tid & 7;
      if (t < tc) {
        const int n = nb * 8 + t;
        const int node = (n == 0) ? 0 : (1 + c * NSP + (n - 1));
        const unsigned short* src = (tid < 64 ? ksrc : vsrc) + (size_t)node * 64 + cc * 8;
        *(uint4*)((tid < 64 ? kv8 : vv8) + t * 64 + cc * 8) = *(const uint4*)src;
      }
    }
    __syncthreads();
    if (tid < 64) {
      #pragma unroll
      for (int t = 0; t < 8; ++t) {
        const float kd = (t < tc) ? b2f(kv8[t * 64 + tid]) : 0.f;
        float s = kd * kd;
        #pragma unroll
        for (int off = 32; off; off >>= 1) s += __shfl_xor(s, off);
        if (tid == 0) diag8[t] = HDN2 * s;
      }
    }
    __syncthreads();
    float dot0[8], dot1[8];
    #pragma unroll
    for (int t = 0; t < 8; ++t) { dot0[t] = 0.f; dot1[t] = 0.f; }
    #pragma unroll
    for (int d0 = 0; d0 < 64; d0 += 8) {
      const bf16x8 p0 = *(const bf16x8*)&projL[tid * 72 + d0];
      float pf0[8], pf1[8];
      #pragma unroll
      for (int j = 0; j < 8; ++j) pf0[j] = (float)p0[j];
      if (m1ok) {
        const bf16x8 p1 = *(const bf16x8*)&projL[(256 + tid) * 72 + d0];
        #pragma unroll
        for (int j = 0; j < 8; ++j) pf1[j] = (float)p1[j];
      } else {
        #pragma unroll
        for (int j = 0; j < 8; ++j) pf1[j] = 0.f;
      }
      #pragma unroll
      for (int t = 0; t < 8; ++t) {
        const bf16x8 kc = *(const bf16x8*)&kv8[t * 64 + d0];
        #pragma unroll
        for (int j = 0; j < 8; ++j) {
          const float kf = (float)kc[j];
          dot0[t] += kf * pf0[j];
          if (m1ok) dot1[t] += kf * pf1[j];
        }
      }
    }
    #pragma unroll
    for (int t = 0; t < 8; ++t) {
      const float kp0 = (t < tc) ? RATIO * (expf(DN * dot0[t] - diag8[t] - gm) + EPSV) : 0.f;
      prowT[tid * 12 + t] = kp0;
      ks0 += kp0;
      if (m1ok) {
        const float kp1 = (t < tc) ? RATIO * (expf(DN * dot1[t] - diag8[t] - gm) + EPSV) : 0.f;
        prowT[(256 + tid) * 12 + t] = kp1;
        ks1 += kp1;
      }
    }
    __syncthreads();
    float vr[8];
    #pragma unroll
    for (int t = 0; t < 8; ++t) vr[t] = (t < tc) ? b2f(vv8[t * 64 + dcl]) : 0.f;
    #pragma unroll
    for (int i = 0; i < 67; ++i) {
      const int m = wv + 4 * i;
      if (m < MF) {
        const f32x4 pa = *(const f32x4*)&prowT[m * 12];
        const f32x4 pb = *(const f32x4*)&prowT[m * 12 + 4];
        ctx_r[i] += pa[0] * vr[0] + pa[1] * vr[1] + pa[2] * vr[2] + pa[3] * vr[3]
                  + pb[0] * vr[4] + pb[1] * vr[5] + pb[2] * vr[6] + pb[3] * vr[7];
      }
    }
  }

  // ================= phase B: queries -> output ===================
  for (int nb = 0; nb < 25; ++nb) {
    const int tc = (196 - nb * 8 < 8) ? (196 - nb * 8) : 8;
    if (tc <= 0) break;
    __syncthreads();
    if (tid < 64) {
      const int t = tid >> 3, cc = tid & 7;
      if (t < tc) {
        const int node = 1 + c * NSP + nb * 8 + t;
        *(uint4*)&kv8[t * 64 + cc * 8] = *(const uint4*)(qsrc + (size_t)node * 64 + cc * 8);
      }
    }
    __syncthreads();
    if (tid < 64) {
      #pragma unroll
      for (int t = 0; t < 8; ++t) {
        const float qd = (t < tc) ? b2f(kv8[t * 64 + tid]) : 0.f;
        float s = qd * qd;
        #pragma unroll
        for (int off = 32; off; off >>= 1) s += __shfl_xor(s, off);
        if (tid == 0) diag8[t] = HDN2 * s;
      }
    }
    __syncthreads();
    float dot0[8], dot1[8];
    #pragma unroll
    for (int t = 0; t < 8; ++t) { dot0[t] = 0.f; dot1[t] = 0.f; }
    #pragma unroll
    for (int d0 = 0; d0 < 64; d0 += 8) {
      const bf16x8 p0 = *(const bf16x8*)&projL[tid * 72 + d0];
      float pf0[8], pf1[8];
      #pragma unroll
      for (int j = 0; j < 8; ++j) pf0[j] = (float)p0[j];
      if (m1ok) {
        const bf16x8 p1 = *(const bf16x8*)&projL[(256 + tid) * 72 + d0];
        #pragma unroll
        for (int j = 0; j < 8; ++j) pf1[j] = (float)p1[j];
      } else {
        #pragma unroll
        for (int j = 0; j < 8; ++j) pf1[j] = 0.f;
      }
      #pragma unroll
      for (int t = 0; t < 8; ++t) {
        const bf16x8 kc = *(const bf16x8*)&kv8[t * 64 + d0];
        #pragma unroll
        for (int j = 0; j < 8; ++j) {
          const float kf = (float)kc[j];
          dot0[t] += kf * pf0[j];
          if (m1ok) dot1[t] += kf * pf1[j];
        }
      }
    }
    float dd0[8], dd1[8];
    #pragma unroll
    for (int t = 0; t < 8; ++t) { dd0[t] = DN * dot0[t]; dd1[t] = DN * dot1[t]; }
    #pragma unroll
    for (int t = 0; t < 8; ++t) {
      float v = dd0[t];
      if (m1ok) v = fmaxf(v, dd1[t]);
      #pragma unroll
      for (int off = 32; off; off >>= 1) v = fmaxf(v, __shfl_xor(v, off));
      if ((tid & 63) == 0) sredA[t][wv] = v;
    }
    __syncthreads();
    #pragma unroll
    for (int t = 0; t < 8; ++t) {
      const float rmax = fmaxf(fmaxf(sredA[t][0], sredA[t][1]),
                               fmaxf(sredA[t][2], sredA[t][3]));
      const float e0 = (t < tc) ? RATIO * (expf(dd0[t] - diag8[t] - rmax) + EPSV) : 0.f;
      prowT[tid * 12 + t] = e0;
      float dp = e0 * ks0;
      if (m1ok) {
        const float e1 = (t < tc) ? RATIO * (expf(dd1[t] - diag8[t] - rmax) + EPSV) : 0.f;
        prowT[(256 + tid) * 12 + t] = e1;
        dp += e1 * ks1;
      }
      #pragma unroll
      for (int off = 32; off; off >>= 1) dp += __shfl_xor(dp, off);
      if ((tid & 63) == 0) sredD[t][wv] = dp;
    }
    __syncthreads();
    float part[8];
    #pragma unroll
    for (int t = 0; t < 8; ++t) part[t] = 0.f;
    #pragma unroll
    for (int i = 0; i < 67; ++i) {
      const int m = wv + 4 * i;
      if (m < MF) {
        const f32x4 pa = *(const f32x4*)&prowT[m * 12];
        const f32x4 pb = *(const f32x4*)&prowT[m * 12 + 4];
        const float cr = ctx_r[i];
        part[0] += pa[0] * cr; part[1] += pa[1] * cr;
        part[2] += pa[2] * cr; part[3] += pa[3] * cr;
        part[4] += pb[0] * cr; part[5] += pb[1] * cr;
        part[6] += pb[2] * cr; part[7] += pb[3] * cr;
      }
    }
    #pragma unroll
    for (int t = 0; t < 8; ++t) pbuf[t][wv][dcl] = part[t];
    __syncthreads();
    for (int s = tid; s < 512; s += 256) {
      const int t = s >> 6, d = s & 63;
      if (t < tc) {
        const float dsum = sredD[t][0] + sredD[t][1] + sredD[t][2] + sredD[t][3];
        const float o = (pbuf[t][0][d] + pbuf[t][1][d] + pbuf[t][2][d] + pbuf[t][3][d]) / dsum;
        const int node = 1 + c * NSP + nb * 8 + t;
        attnb[((size_t)bb * NTOK + node) * DIM + hh * DH + d] = f2b(o);
      }
    }
  }
}

}  // namespace

extern "C" void kernel_launch(void* const* d_in, const int* in_sizes, int n_in,
                              void* d_out, int out_size, void* d_ws, size_t ws_size,
                              hipStream_t stream) {
  (void)in_sizes; (void)n_in; (void)out_size; (void)ws_size;
  const float* x    = (const float*)d_in[0];
  const float* wqkv = (const float*)d_in[1];
  const float* wout = (const float*)d_in[2];
  const float* proj = (const float*)d_in[3];
  float* out = (float*)d_out;

  const size_t QKV = (size_t)BH * NTOK * DH;  // 12,849,152 elements
  unsigned short* qb    = (unsigned short*)d_ws;
  unsigned short* kb    = qb + QKV;
  unsigned short* vb    = kb + QKV;
  unsigned short* attnb = vb + QKV;
  float* pmax = (float*)(attnb + QKV);
  float* gmax = pmax + NG;
  // total ws use identical to the proven round-2 layout (~102.8 MB)

  const dim3 blk(256);
  k_qkv    <<<dim3(197, 12), blk, 0, stream>>>(x, wqkv, qb, kb, vb);
  k_cls    <<<dim3(BH),      blk, 0, stream>>>(qb, kb, vb, attnb);
  k_keymax <<<dim3(NG),      blk, 0, stream>>>(kb, proj, pmax);
  k_maxred <<<dim3(1),       blk, 0, stream>>>(pmax, gmax);
  k_fused  <<<dim3(NG),      blk, 0, stream>>>(qb, kb, vb, proj, gmax, attnb);
  k_out    <<<dim3(197, 4),  blk, 0, stream>>>(attnb, wout, out);
}

// Round 4
// 876.905 us; speedup vs baseline: 6.6597x; 6.6597x over previous
//
#include <hip/hip_runtime.h>
#include <hip/hip_bf16.h>

namespace {

typedef __bf16 bf16x8 __attribute__((ext_vector_type(8)));
typedef float  f32x4  __attribute__((ext_vector_type(4)));
typedef unsigned short ushort8 __attribute__((ext_vector_type(8)));

constexpr int NTOK  = 3137;          // 1 + 16*196
constexpr int NH    = 8;
constexpr int DH    = 64;
constexpr int BH    = 64;            // BATCH*NH
constexpr int MROWS = 8 * NTOK;      // 25096
constexpr int NROWS = BH * NTOK;     // 200768 (rows of kb)
constexpr int MF    = 266;           // NB_FEATURES
constexpr int MP    = 320;           // padded m (5 frags x 4 waves x 16)
constexpr int DP    = 80;            // padded d: 64 data + 1 ksum + 15 pad
constexpr int NMAXB = NROWS / 64;    // 3137 keymax blocks

constexpr float DN     = 0.35355339059327379f;  // 64^-0.25
constexpr float HDN2   = 0.0625f;               // 0.5 * 64^-0.5
constexpr float RATIO  = 0.0613139368f;         // 266^-0.5
constexpr float EPSV   = 1.0e-4f;
constexpr float QSCALE = 0.125f;                // 64^-0.5

__device__ __forceinline__ float b2f(unsigned short u) {
  union { unsigned int i; float f; } cv;
  cv.i = ((unsigned int)u) << 16;
  return cv.f;
}
__device__ __forceinline__ unsigned short f2b(float f) {
  __hip_bfloat16 h = __float2bfloat16(f);
  union { __hip_bfloat16 h; unsigned short u; } cv;
  cv.h = h;
  return cv.u;
}
__device__ __forceinline__ unsigned int pk2(float a, float b) {
  return (unsigned int)f2b(a) | ((unsigned int)f2b(b) << 16);
}

// ============ MFMA GEMM 1: qkv = x @ W_qkv, scatter bf16 q/k/v ==============
__global__ __launch_bounds__(256) void k_qkv(
    const float* __restrict__ x,   // [MROWS][512]
    const float* __restrict__ w,   // [512][1536]
    unsigned short* __restrict__ qb, unsigned short* __restrict__ kb,
    unsigned short* __restrict__ vb)
{
  __shared__ alignas(16) unsigned short As[128 * 72];  // [m][k] pad 72
  __shared__ alignas(16) unsigned short Bs[128 * 72];  // [n][k] pad 72
  const int bm = blockIdx.x, bn = blockIdx.y;
  const int tid = threadIdx.x;
  const int lane = tid & 63, wid = tid >> 6;
  const int wr = wid >> 1, wc = wid & 1;
  const int row0 = bm * 128, col0 = bn * 128;
  const int l15 = lane & 15, l4 = lane >> 4;

  f32x4 acc[4][4];
  #pragma unroll
  for (int i = 0; i < 4; ++i)
    #pragma unroll
    for (int j = 0; j < 4; ++j) acc[i][j] = f32x4{0.f, 0.f, 0.f, 0.f};

  for (int kt = 0; kt < 512; kt += 64) {
    {
      const int r = tid >> 1, k0 = (tid & 1) * 32;
      const int gr = row0 + r;
      if (gr < MROWS) {
        const float* src = x + (size_t)gr * 512 + kt + k0;
        #pragma unroll
        for (int cch = 0; cch < 4; ++cch) {
          const float4 f0 = *(const float4*)(src + cch * 8);
          const float4 f1 = *(const float4*)(src + cch * 8 + 4);
          uint4 u;
          u.x = pk2(f0.x, f0.y); u.y = pk2(f0.z, f0.w);
          u.z = pk2(f1.x, f1.y); u.w = pk2(f1.z, f1.w);
          *(uint4*)&As[r * 72 + k0 + cch * 8] = u;
        }
      } else {
        const uint4 z = {0, 0, 0, 0};
        #pragma unroll
        for (int cch = 0; cch < 4; ++cch) *(uint4*)&As[r * 72 + k0 + cch * 8] = z;
      }
    }
    {
      const int kk = tid >> 2, j0 = (tid & 3) * 32;
      const float* src = w + (size_t)(kt + kk) * 1536 + col0 + j0;
      #pragma unroll
      for (int jc = 0; jc < 32; jc += 4) {
        const float4 f = *(const float4*)(src + jc);
        Bs[(j0 + jc + 0) * 72 + kk] = f2b(f.x);
        Bs[(j0 + jc + 1) * 72 + kk] = f2b(f.y);
        Bs[(j0 + jc + 2) * 72 + kk] = f2b(f.z);
        Bs[(j0 + jc + 3) * 72 + kk] = f2b(f.w);
      }
    }
    __syncthreads();
    #pragma unroll
    for (int ks = 0; ks < 2; ++ks) {
      bf16x8 af[4], bfr[4];
      #pragma unroll
      for (int i = 0; i < 4; ++i)
        af[i] = *(const bf16x8*)&As[(wr * 64 + i * 16 + l15) * 72 + ks * 32 + l4 * 8];
      #pragma unroll
      for (int i = 0; i < 4; ++i)
        bfr[i] = *(const bf16x8*)&Bs[(wc * 64 + i * 16 + l15) * 72 + ks * 32 + l4 * 8];
      #pragma unroll
      for (int mi = 0; mi < 4; ++mi)
        #pragma unroll
        for (int ni = 0; ni < 4; ++ni)
          acc[mi][ni] = __builtin_amdgcn_mfma_f32_16x16x32_bf16(
              af[mi], bfr[ni], acc[mi][ni], 0, 0, 0);
    }
    __syncthreads();
  }
  #pragma unroll
  for (int mi = 0; mi < 4; ++mi) {
    #pragma unroll
    for (int r = 0; r < 4; ++r) {
      const int grow = row0 + wr * 64 + mi * 16 + l4 * 4 + r;
      if (grow < MROWS) {
        const int bb = grow / NTOK, n = grow - bb * NTOK;
        #pragma unroll
        for (int ni = 0; ni < 4; ++ni) {
          const int gc = col0 + wc * 64 + ni * 16 + l15;
          const int which = gc >> 9;
          const int col = gc & 511;
          const int hh = col >> 6, d = col & 63;
          const size_t off = (size_t)((bb * NH + hh) * NTOK + n) * DH + d;
          const float vv = acc[mi][ni][r];
          if (which == 0)      qb[off] = f2b(vv * QSCALE);
          else if (which == 1) kb[off] = f2b(vv);
          else                 vb[off] = f2b(vv);
        }
      }
    }
  }
}

// ============ MFMA GEMM 2: out = attn(bf16) @ W_out -> fp32 =================
__global__ __launch_bounds__(256) void k_out(
    const unsigned short* __restrict__ a,   // bf16 [MROWS][512]
    const float* __restrict__ w,            // fp32 [512][512]
    float* __restrict__ out)                // fp32 [MROWS][512]
{
  __shared__ alignas(16) unsigned short As[128 * 72];
  __shared__ alignas(16) unsigned short Bs[128 * 72];
  const int bm = blockIdx.x, bn = blockIdx.y;
  const int tid = threadIdx.x;
  const int lane = tid & 63, wid = tid >> 6;
  const int wr = wid >> 1, wc = wid & 1;
  const int row0 = bm * 128, col0 = bn * 128;
  const int l15 = lane & 15, l4 = lane >> 4;

  f32x4 acc[4][4];
  #pragma unroll
  for (int i = 0; i < 4; ++i)
    #pragma unroll
    for (int j = 0; j < 4; ++j) acc[i][j] = f32x4{0.f, 0.f, 0.f, 0.f};

  for (int kt = 0; kt < 512; kt += 64) {
    {
      const int r = tid >> 1, k0 = (tid & 1) * 32;
      const int gr = row0 + r;
      if (gr < MROWS) {
        const unsigned short* src = a + (size_t)gr * 512 + kt + k0;
        #pragma unroll
        for (int cch = 0; cch < 4; ++cch)
          *(uint4*)&As[r * 72 + k0 + cch * 8] = *(const uint4*)(src + cch * 8);
      } else {
        const uint4 z = {0, 0, 0, 0};
        #pragma unroll
        for (int cch = 0; cch < 4; ++cch) *(uint4*)&As[r * 72 + k0 + cch * 8] = z;
      }
    }
    {
      const int kk = tid >> 2, j0 = (tid & 3) * 32;
      const float* src = w + (size_t)(kt + kk) * 512 + col0 + j0;
      #pragma unroll
      for (int jc = 0; jc < 32; jc += 4) {
        const float4 f = *(const float4*)(src + jc);
        Bs[(j0 + jc + 0) * 72 + kk] = f2b(f.x);
        Bs[(j0 + jc + 1) * 72 + kk] = f2b(f.y);
        Bs[(j0 + jc + 2) * 72 + kk] = f2b(f.z);
        Bs[(j0 + jc + 3) * 72 + kk] = f2b(f.w);
      }
    }
    __syncthreads();
    #pragma unroll
    for (int ks = 0; ks < 2; ++ks) {
      bf16x8 af[4], bfr[4];
      #pragma unroll
      for (int i = 0; i < 4; ++i)
        af[i] = *(const bf16x8*)&As[(wr * 64 + i * 16 + l15) * 72 + ks * 32 + l4 * 8];
      #pragma unroll
      for (int i = 0; i < 4; ++i)
        bfr[i] = *(const bf16x8*)&Bs[(wc * 64 + i * 16 + l15) * 72 + ks * 32 + l4 * 8];
      #pragma unroll
      for (int mi = 0; mi < 4; ++mi)
        #pragma unroll
        for (int ni = 0; ni < 4; ++ni)
          acc[mi][ni] = __builtin_amdgcn_mfma_f32_16x16x32_bf16(
              af[mi], bfr[ni], acc[mi][ni], 0, 0, 0);
    }
    __syncthreads();
  }
  #pragma unroll
  for (int mi = 0; mi < 4; ++mi) {
    #pragma unroll
    for (int r = 0; r < 4; ++r) {
      const int grow = row0 + wr * 64 + mi * 16 + l4 * 4 + r;
      if (grow < MROWS) {
        #pragma unroll
        for (int ni = 0; ni < 4; ++ni) {
          const int gc = col0 + wc * 64 + ni * 16 + l15;
          out[(size_t)grow * 512 + gc] = acc[mi][ni][r];
        }
      }
    }
  }
}

// ---------------- cls-token softmax attention (unchanged, works) ------------
__global__ __launch_bounds__(256) void k_cls(
    const unsigned short* __restrict__ qb, const unsigned short* __restrict__ kb,
    const unsigned short* __restrict__ vb, unsigned short* __restrict__ attnb)
{
  __shared__ float sim[NTOK];
  __shared__ float qv[DH];
  __shared__ float sred[4], sred2[4];
  __shared__ float pbuf[4][DH];
  const int bh = blockIdx.x, tid = threadIdx.x;
  const int wv = tid >> 6, dcl = tid & 63;
  const unsigned short* ks = kb + (size_t)bh * NTOK * DH;
  const unsigned short* vs = vb + (size_t)bh * NTOK * DH;
  if (tid < DH) qv[tid] = b2f(qb[(size_t)bh * NTOK * DH + tid]);
  __syncthreads();
  float lmax = -1e30f;
  for (int j = tid; j < NTOK; j += 256) {
    const unsigned short* kr = ks + (size_t)j * DH;
    float dot = 0.f;
    #pragma unroll
    for (int d0 = 0; d0 < DH; d0 += 8) {
      const bf16x8 kv = *(const bf16x8*)(kr + d0);
      #pragma unroll
      for (int j2 = 0; j2 < 8; ++j2) dot += qv[d0 + j2] * (float)kv[j2];
    }
    sim[j] = dot;
    lmax = fmaxf(lmax, dot);
  }
  #pragma unroll
  for (int off = 32; off; off >>= 1) lmax = fmaxf(lmax, __shfl_xor(lmax, off));
  if ((tid & 63) == 0) sred[wv] = lmax;
  __syncthreads();
  const float mx = fmaxf(fmaxf(sred[0], sred[1]), fmaxf(sred[2], sred[3]));
  float lsum = 0.f;
  for (int j = tid; j < NTOK; j += 256) {
    const float p = expf(sim[j] - mx);
    sim[j] = p;
    lsum += p;
  }
  #pragma unroll
  for (int off = 32; off; off >>= 1) lsum += __shfl_xor(lsum, off);
  __syncthreads();
  if ((tid & 63) == 0) sred2[wv] = lsum;
  __syncthreads();
  const float tot = sred2[0] + sred2[1] + sred2[2] + sred2[3];
  float accv = 0.f;
  for (int j = wv; j < NTOK; j += 4) accv += sim[j] * b2f(vs[(size_t)j * DH + dcl]);
  pbuf[wv][dcl] = accv;
  __syncthreads();
  if (tid < DH) {
    const float o = (pbuf[0][tid] + pbuf[1][tid] + pbuf[2][tid] + pbuf[3][tid]) / tot;
    const int bb = bh >> 3, hh = bh & 7;
    attnb[((size_t)bb * NTOK + 0) * 512 + hh * DH + tid] = f2b(o);
  }
}

// ---------------- MFMA global key-projection max ----------------------------
// Each block: 64 rows of kb x all 266 m. Wave w handles m in [80w, 80w+80).
__global__ __launch_bounds__(256) void k_keymax(
    const unsigned short* __restrict__ kb, const float* __restrict__ proj,
    float* __restrict__ pmax)
{
  __shared__ alignas(16) unsigned short projL[MP * 64];
  __shared__ float red[4];
  const int blk = blockIdx.x, tid = threadIdx.x;
  const int lane = tid & 63, wave = tid >> 6;
  const int l15 = lane & 15, l4 = lane >> 4;
  const int mw0 = wave * 80;
  for (int idx = tid; idx < MP * 64; idx += 256) {
    const int m = idx >> 6, d = idx & 63;
    projL[idx] = (m < MF) ? f2b(proj[m * 64 + d]) : (unsigned short)0;
  }
  __syncthreads();
  const int row0 = blk * 64;
  bf16x8 bfrag[4][2];
  #pragma unroll
  for (int tf = 0; tf < 4; ++tf) {
    int gr = row0 + tf * 16 + l15;
    if (gr >= NROWS) gr = NROWS - 1;
    #pragma unroll
    for (int ks = 0; ks < 2; ++ks)
      bfrag[tf][ks] = *(const bf16x8*)(kb + (size_t)gr * 64 + ks * 32 + l4 * 8);
  }
  f32x4 acc[5][4];
  #pragma unroll
  for (int i = 0; i < 5; ++i)
    #pragma unroll
    for (int j = 0; j < 4; ++j) acc[i][j] = f32x4{0.f, 0.f, 0.f, 0.f};
  #pragma unroll
  for (int mf = 0; mf < 5; ++mf) {
    const bf16x8 a0 = *(const bf16x8*)&projL[(mw0 + mf * 16 + l15) * 64 + l4 * 8];
    const bf16x8 a1 = *(const bf16x8*)&projL[(mw0 + mf * 16 + l15) * 64 + 32 + l4 * 8];
    #pragma unroll
    for (int tf = 0; tf < 4; ++tf) {
      acc[mf][tf] = __builtin_amdgcn_mfma_f32_16x16x32_bf16(a0, bfrag[tf][0], acc[mf][tf], 0, 0, 0);
      acc[mf][tf] = __builtin_amdgcn_mfma_f32_16x16x32_bf16(a1, bfrag[tf][1], acc[mf][tf], 0, 0, 0);
    }
  }
  float lm = -3e38f;
  #pragma unroll
  for (int tf = 0; tf < 4; ++tf) {
    const bool colok = (row0 + tf * 16 + l15) < NROWS;
    #pragma unroll
    for (int mf = 0; mf < 5; ++mf)
      #pragma unroll
      for (int r = 0; r < 4; ++r) {
        const int m = mw0 + mf * 16 + l4 * 4 + r;
        if (colok && m < MF) lm = fmaxf(lm, DN * acc[mf][tf][r]);
      }
  }
  #pragma unroll
  for (int off = 32; off; off >>= 1) lm = fmaxf(lm, __shfl_xor(lm, off));
  if (lane == 0) red[wave] = lm;
  __syncthreads();
  if (tid == 0) pmax[blk] = fmaxf(fmaxf(red[0], red[1]), fmaxf(red[2], red[3]));
}

__global__ __launch_bounds__(256) void k_maxred(
    const float* __restrict__ pmax, float* __restrict__ gmax)
{
  __shared__ float sred[4];
  float v = -3e38f;
  for (int i = threadIdx.x; i < NMAXB; i += 256) v = fmaxf(v, pmax[i]);
  #pragma unroll
  for (int off = 32; off; off >>= 1) v = fmaxf(v, __shfl_xor(v, off));
  if ((threadIdx.x & 63) == 0) sred[threadIdx.x >> 6] = v;
  __syncthreads();
  if (threadIdx.x == 0)
    gmax[0] = fmaxf(fmaxf(sred[0], sred[1]), fmaxf(sred[2], sred[3]));
}

// ------- fused per-group, full-MFMA: ctx + ksum + query + output ------------
// 4 waves; wave owns m-slice [80w, 80w+80) for stages 1/2/3 and token-slice
// [16w,16w+16) for stage 4. ksum folded in as ones-column 64 of V'.
__global__ __launch_bounds__(256, 1) void k_fused(
    const unsigned short* __restrict__ qb, const unsigned short* __restrict__ kb,
    const unsigned short* __restrict__ vb, const float* __restrict__ proj,
    const float* __restrict__ gmaxp, unsigned short* __restrict__ attnb)
{
  __shared__ alignas(16) unsigned short projL[MP * 64];  // 40 KB [m][d]
  __shared__ alignas(16) unsigned short kpqp[MP * 64];   // 40 KB: A KP_T[m][t]; B QP[t][m]
  __shared__ alignas(16) unsigned short ctxT[DP * MP];   // 50 KB [d][m]; head doubles as vT[d][t]
  __shared__ float diag_l[64];
  __shared__ float rmax_l[4][64];
  __shared__ float denom_l[64];

  const int g = blockIdx.x, bh = g >> 4, c = g & 15;
  const int bb = bh >> 3, hh = bh & 7;
  const int tid = threadIdx.x;
  const int lane = tid & 63, wave = tid >> 6;
  const int l15 = lane & 15, l4 = lane >> 4;
  const int mw0 = wave * 80;
  const float gm = gmaxp[0];
  unsigned short* vT = ctxT;  // [DP][64] region during phase A

  for (int idx = tid; idx < MP * 64; idx += 256) {
    const int m = idx >> 6, d = idx & 63;
    projL[idx] = (m < MF) ? f2b(proj[m * 64 + d]) : (unsigned short)0;
  }
  for (int i = tid; i < (DP - 65) * 64; i += 256) vT[65 * 64 + i] = 0;

  const unsigned short* ksrc = kb + (size_t)bh * NTOK * 64;
  const unsigned short* vsrc = vb + (size_t)bh * NTOK * 64;
  const unsigned short* qsrc = qb + (size_t)bh * NTOK * 64;

  f32x4 ctxacc[5][5];
  #pragma unroll
  for (int i = 0; i < 5; ++i)
    #pragma unroll
    for (int j = 0; j < 5; ++j) ctxacc[i][j] = f32x4{0.f, 0.f, 0.f, 0.f};

  // =============== phase A: 4 key tiles (197 tokens) ===============
  for (int kt = 0; kt < 4; ++kt) {
    const int tc = (kt < 3) ? 64 : 5;
    __syncthreads();
    {  // stage vT (transposed V) + ones row
      const int t = tid >> 2, d0 = (tid & 3) * 16;
      const int n = kt * 64 + t;
      if (n < 197) {
        const int node = (n == 0) ? 0 : 1 + c * 196 + (n - 1);
        #pragma unroll
        for (int h = 0; h < 2; ++h) {
          const ushort8 v = *(const ushort8*)(vsrc + (size_t)node * 64 + d0 + h * 8);
          #pragma unroll
          for (int j = 0; j < 8; ++j) vT[(d0 + h * 8 + j) * 64 + t] = v[j];
        }
      } else {
        #pragma unroll
        for (int h = 0; h < 16; ++h) vT[(d0 + h) * 64 + t] = 0;
      }
      if (tid < 64) vT[64 * 64 + tid] = (tid < tc) ? (unsigned short)0x3F80 : (unsigned short)0;
    }
    if (tid < 64) {  // diag from K rows
      const int n = kt * 64 + tid;
      const int nn = (n < 197) ? n : 0;
      const int node = (nn == 0) ? 0 : 1 + c * 196 + (nn - 1);
      const unsigned short* kr = ksrc + (size_t)node * 64;
      float s = 0.f;
      #pragma unroll
      for (int d0 = 0; d0 < 64; d0 += 8) {
        const bf16x8 v = *(const bf16x8*)(kr + d0);
        #pragma unroll
        for (int j = 0; j < 8; ++j) { const float f = (float)v[j]; s += f * f; }
      }
      diag_l[tid] = HDN2 * s;
    }
    __syncthreads();
    // stage 1: DD_T[m][token] = proj . K^T
    bf16x8 bfrag[4][2];
    #pragma unroll
    for (int tf = 0; tf < 4; ++tf) {
      const int n = kt * 64 + tf * 16 + l15;
      const int nn = (n < 197) ? n : 0;
      const int node = (nn == 0) ? 0 : 1 + c * 196 + (nn - 1);
      #pragma unroll
      for (int ks = 0; ks < 2; ++ks)
        bfrag[tf][ks] = *(const bf16x8*)(ksrc + (size_t)node * 64 + ks * 32 + l4 * 8);
    }
    f32x4 acc[5][4];
    #pragma unroll
    for (int i = 0; i < 5; ++i)
      #pragma unroll
      for (int j = 0; j < 4; ++j) acc[i][j] = f32x4{0.f, 0.f, 0.f, 0.f};
    #pragma unroll
    for (int mf = 0; mf < 5; ++mf) {
      const bf16x8 a0 = *(const bf16x8*)&projL[(mw0 + mf * 16 + l15) * 64 + l4 * 8];
      const bf16x8 a1 = *(const bf16x8*)&projL[(mw0 + mf * 16 + l15) * 64 + 32 + l4 * 8];
      #pragma unroll
      for (int tf = 0; tf < 4; ++tf) {
        acc[mf][tf] = __builtin_amdgcn_mfma_f32_16x16x32_bf16(a0, bfrag[tf][0], acc[mf][tf], 0, 0, 0);
        acc[mf][tf] = __builtin_amdgcn_mfma_f32_16x16x32_bf16(a1, bfrag[tf][1], acc[mf][tf], 0, 0, 0);
      }
    }
    // kp = f(dd) -> KP_T[m][t]
    #pragma unroll
    for (int mf = 0; mf < 5; ++mf)
      #pragma unroll
      for (int tf = 0; tf < 4; ++tf) {
        const int t = tf * 16 + l15;
        const int n = kt * 64 + t;
        #pragma unroll
        for (int r = 0; r < 4; ++r) {
          const int m = mw0 + mf * 16 + l4 * 4 + r;
          float kp = 0.f;
          if (m < MF && n < 197)
            kp = RATIO * (expf(DN * acc[mf][tf][r] - diag_l[t] - gm) + EPSV);
          kpqp[m * 64 + t] = f2b(kp);
        }
      }
    __syncthreads();
    // stage 2: ctx += KP_T . V'
    #pragma unroll
    for (int ks = 0; ks < 2; ++ks) {
      bf16x8 a2[5];
      #pragma unroll
      for (int mf = 0; mf < 5; ++mf)
        a2[mf] = *(const bf16x8*)&kpqp[(mw0 + mf * 16 + l15) * 64 + ks * 32 + l4 * 8];
      #pragma unroll
      for (int df = 0; df < 5; ++df) {
        const bf16x8 b2 = *(const bf16x8*)&vT[(df * 16 + l15) * 64 + ks * 32 + l4 * 8];
        #pragma unroll
        for (int mf = 0; mf < 5; ++mf)
          ctxacc[mf][df] = __builtin_amdgcn_mfma_f32_16x16x32_bf16(a2[mf], b2, ctxacc[mf][df], 0, 0, 0);
      }
    }
  }
  // write CTX_T[d][m] (overwrites vT region; safe after barrier)
  __syncthreads();
  #pragma unroll
  for (int mf = 0; mf < 5; ++mf)
    #pragma unroll
    for (int df = 0; df < 5; ++df)
      #pragma unroll
      for (int r = 0; r < 4; ++r) {
        const int m = mw0 + mf * 16 + l4 * 4 + r;
        const int d = df * 16 + l15;
        ctxT[d * MP + m] = f2b(ctxacc[mf][df][r]);
      }

  // =============== phase B: 4 query tiles (196 tokens) ===============
  for (int qt = 0; qt < 4; ++qt) {
    const int tc = (qt < 3) ? 64 : 4;
    __syncthreads();
    if (tid < 64) {  // diag from Q rows
      const int n = qt * 64 + tid;
      const int nn = (n < 196) ? n : 0;
      const int node = 1 + c * 196 + nn;
      const unsigned short* qr = qsrc + (size_t)node * 64;
      float s = 0.f;
      #pragma unroll
      for (int d0 = 0; d0 < 64; d0 += 8) {
        const bf16x8 v = *(const bf16x8*)(qr + d0);
        #pragma unroll
        for (int j = 0; j < 8; ++j) { const float f = (float)v[j]; s += f * f; }
      }
      diag_l[tid] = HDN2 * s;
    }
    __syncthreads();
    // stage 3: DD_T = proj . Q^T
    bf16x8 bfrag[4][2];
    #pragma unroll
    for (int tf = 0; tf < 4; ++tf) {
      const int n = qt * 64 + tf * 16 + l15;
      const int nn = (n < 196) ? n : 0;
      const int node = 1 + c * 196 + nn;
      #pragma unroll
      for (int ks = 0; ks < 2; ++ks)
        bfrag[tf][ks] = *(const bf16x8*)(qsrc + (size_t)node * 64 + ks * 32 + l4 * 8);
    }
    f32x4 acc[5][4];
    #pragma unroll
    for (int i = 0; i < 5; ++i)
      #pragma unroll
      for (int j = 0; j < 4; ++j) acc[i][j] = f32x4{0.f, 0.f, 0.f, 0.f};
    #pragma unroll
    for (int mf = 0; mf < 5; ++mf) {
      const bf16x8 a0 = *(const bf16x8*)&projL[(mw0 + mf * 16 + l15) * 64 + l4 * 8];
      const bf16x8 a1 = *(const bf16x8*)&projL[(mw0 + mf * 16 + l15) * 64 + 32 + l4 * 8];
      #pragma unroll
      for (int tf = 0; tf < 4; ++tf) {
        acc[mf][tf] = __builtin_amdgcn_mfma_f32_16x16x32_bf16(a0, bfrag[tf][0], acc[mf][tf], 0, 0, 0);
        acc[mf][tf] = __builtin_amdgcn_mfma_f32_16x16x32_bf16(a1, bfrag[tf][1], acc[mf][tf], 0, 0, 0);
      }
    }
    // per-token rowmax over wave's m-slice -> cross-wave via LDS
    #pragma unroll
    for (int tf = 0; tf < 4; ++tf) {
      float v = -3e38f;
      #pragma unroll
      for (int mf = 0; mf < 5; ++mf)
        #pragma unroll
        for (int r = 0; r < 4; ++r) {
          const int m = mw0 + mf * 16 + l4 * 4 + r;
          if (m < MF) v = fmaxf(v, DN * acc[mf][tf][r]);
        }
      v = fmaxf(v, __shfl_xor(v, 16));
      v = fmaxf(v, __shfl_xor(v, 32));
      if (l4 == 0) rmax_l[wave][tf * 16 + l15] = v;
    }
    __syncthreads();
    // qp = f(dd) -> QP[t][m]
    #pragma unroll
    for (int tf = 0; tf < 4; ++tf) {
      const int t = tf * 16 + l15;
      const float rm = fmaxf(fmaxf(rmax_l[0][t], rmax_l[1][t]),
                             fmaxf(rmax_l[2][t], rmax_l[3][t]));
      const float dg = diag_l[t];
      #pragma unroll
      for (int mf = 0; mf < 5; ++mf)
        #pragma unroll
        for (int r = 0; r < 4; ++r) {
          const int m = mw0 + mf * 16 + l4 * 4 + r;
          float e = 0.f;
          if (m < MF && t < tc)
            e = RATIO * (expf(DN * acc[mf][tf][r] - dg - rm) + EPSV);
          kpqp[t * MP + m] = f2b(e);
        }
    }
    __syncthreads();
    // stage 4: OUT[token][d] = QP . CTX_T^T  (contraction over m)
    f32x4 oacc[5];
    #pragma unroll
    for (int i = 0; i < 5; ++i) oacc[i] = f32x4{0.f, 0.f, 0.f, 0.f};
    #pragma unroll
    for (int ks = 0; ks < 10; ++ks) {
      const bf16x8 a4 = *(const bf16x8*)&kpqp[(wave * 16 + l15) * MP + ks * 32 + l4 * 8];
      #pragma unroll
      for (int df = 0; df < 5; ++df) {
        const bf16x8 b4 = *(const bf16x8*)&ctxT[(df * 16 + l15) * MP + ks * 32 + l4 * 8];
        oacc[df] = __builtin_amdgcn_mfma_f32_16x16x32_bf16(a4, b4, oacc[df], 0, 0, 0);
      }
    }
    if (l15 == 0) {
      #pragma unroll
      for (int r = 0; r < 4; ++r) denom_l[wave * 16 + l4 * 4 + r] = oacc[4][r];
    }
    __syncthreads();
    #pragma unroll
    for (int r = 0; r < 4; ++r) {
      const int t = wave * 16 + l4 * 4 + r;
      if (t < tc) {
        const int node = 1 + c * 196 + qt * 64 + t;
        const float dinv = 1.0f / denom_l[t];
        unsigned short* orow = attnb + ((size_t)bb * NTOK + node) * 512 + hh * 64;
        #pragma unroll
        for (int df = 0; df < 4; ++df)
          orow[df * 16 + l15] = f2b(oacc[df][r] * dinv);
      }
    }
  }
}

}  // namespace

extern "C" void kernel_launch(void* const* d_in, const int* in_sizes, int n_in,
                              void* d_out, int out_size, void* d_ws, size_t ws_size,
                              hipStream_t stream) {
  (void)in_sizes; (void)n_in; (void)out_size; (void)ws_size;
  const float* x    = (const float*)d_in[0];
  const float* wqkv = (const float*)d_in[1];
  const float* wout = (const float*)d_in[2];
  const float* proj = (const float*)d_in[3];
  float* out = (float*)d_out;

  const size_t QKV = (size_t)BH * NTOK * DH;  // 12,849,152 elements
  unsigned short* qb    = (unsigned short*)d_ws;
  unsigned short* kb    = qb + QKV;
  unsigned short* vb    = kb + QKV;
  unsigned short* attnb = vb + QKV;
  float* pmax = (float*)(attnb + QKV);
  float* gmax = pmax + NMAXB;
  // ws use ~102.8 MB (same proven footprint class as round 2/3)

  const dim3 blk(256);
  k_qkv    <<<dim3(197, 12), blk, 0, stream>>>(x, wqkv, qb, kb, vb);
  k_cls    <<<dim3(BH),      blk, 0, stream>>>(qb, kb, vb, attnb);
  k_keymax <<<dim3(NMAXB),   blk, 0, stream>>>(kb, proj, pmax);
  k_maxred <<<dim3(1),       blk, 0, stream>>>(pmax, gmax);
  k_fused  <<<dim3(1024),    blk, 0, stream>>>(qb, kb, vb, proj, gmax, attnb);
  k_out    <<<dim3(197, 4),  blk, 0, stream>>>(attnb, wout, out);
}

// Round 5
// 763.679 us; speedup vs baseline: 7.6471x; 1.1483x over previous
//
#include <hip/hip_runtime.h>
#include <hip/hip_bf16.h>

namespace {

typedef __bf16 bf16x8 __attribute__((ext_vector_type(8)));
typedef float  f32x4  __attribute__((ext_vector_type(4)));
typedef unsigned short ushort8 __attribute__((ext_vector_type(8)));

constexpr int NTOK  = 3137;          // 1 + 16*196
constexpr int NH    = 8;
constexpr int DH    = 64;
constexpr int BH    = 64;            // BATCH*NH
constexpr int MROWS = 8 * NTOK;      // 25096
constexpr int NROWS = BH * NTOK;     // 200768 (rows of kb)
constexpr int MF    = 266;           // NB_FEATURES
constexpr int MP    = 320;           // padded m
constexpr int PK    = 72;            // padded row stride for [x][64] tiles (144 B)
constexpr int PM    = 328;           // padded row stride for [x][320] tiles (656 B)
constexpr int NMAXB = NROWS / 64;    // 3137 keymax blocks

constexpr float DN     = 0.35355339059327379f;  // 64^-0.25
constexpr float HDN2   = 0.0625f;               // 0.5 * 64^-0.5
constexpr float RATIO  = 0.0613139368f;         // 266^-0.5
constexpr float EPSV   = 1.0e-4f;
constexpr float QSCALE = 0.125f;                // 64^-0.5

__device__ __forceinline__ float b2f(unsigned short u) {
  union { unsigned int i; float f; } cv;
  cv.i = ((unsigned int)u) << 16;
  return cv.f;
}
__device__ __forceinline__ unsigned short f2b(float f) {
  __hip_bfloat16 h = __float2bfloat16(f);
  union { __hip_bfloat16 h; unsigned short u; } cv;
  cv.h = h;
  return cv.u;
}
__device__ __forceinline__ unsigned int pk2(float a, float b) {
  return (unsigned int)f2b(a) | ((unsigned int)f2b(b) << 16);
}

// ============ MFMA GEMM 1: qkv = x @ W_qkv, scatter bf16 q/k/v ==============
__global__ __launch_bounds__(256) void k_qkv(
    const float* __restrict__ x,   // [MROWS][512]
    const float* __restrict__ w,   // [512][1536]
    unsigned short* __restrict__ qb, unsigned short* __restrict__ kb,
    unsigned short* __restrict__ vb)
{
  __shared__ alignas(16) unsigned short As[128 * 72];  // [m][k] pad 72
  __shared__ alignas(16) unsigned short Bs[128 * 72];  // [n][k] pad 72
  const int bm = blockIdx.x, bn = blockIdx.y;
  const int tid = threadIdx.x;
  const int lane = tid & 63, wid = tid >> 6;
  const int wr = wid >> 1, wc = wid & 1;
  const int row0 = bm * 128, col0 = bn * 128;
  const int l15 = lane & 15, l4 = lane >> 4;

  f32x4 acc[4][4];
  #pragma unroll
  for (int i = 0; i < 4; ++i)
    #pragma unroll
    for (int j = 0; j < 4; ++j) acc[i][j] = f32x4{0.f, 0.f, 0.f, 0.f};

  for (int kt = 0; kt < 512; kt += 64) {
    {
      const int r = tid >> 1, k0 = (tid & 1) * 32;
      const int gr = row0 + r;
      if (gr < MROWS) {
        const float* src = x + (size_t)gr * 512 + kt + k0;
        #pragma unroll
        for (int cch = 0; cch < 4; ++cch) {
          const float4 f0 = *(const float4*)(src + cch * 8);
          const float4 f1 = *(const float4*)(src + cch * 8 + 4);
          uint4 u;
          u.x = pk2(f0.x, f0.y); u.y = pk2(f0.z, f0.w);
          u.z = pk2(f1.x, f1.y); u.w = pk2(f1.z, f1.w);
          *(uint4*)&As[r * 72 + k0 + cch * 8] = u;
        }
      } else {
        const uint4 z = {0, 0, 0, 0};
        #pragma unroll
        for (int cch = 0; cch < 4; ++cch) *(uint4*)&As[r * 72 + k0 + cch * 8] = z;
      }
    }
    {
      const int kk = tid >> 2, j0 = (tid & 3) * 32;
      const float* src = w + (size_t)(kt + kk) * 1536 + col0 + j0;
      #pragma unroll
      for (int jc = 0; jc < 32; jc += 4) {
        const float4 f = *(const float4*)(src + jc);
        Bs[(j0 + jc + 0) * 72 + kk] = f2b(f.x);
        Bs[(j0 + jc + 1) * 72 + kk] = f2b(f.y);
        Bs[(j0 + jc + 2) * 72 + kk] = f2b(f.z);
        Bs[(j0 + jc + 3) * 72 + kk] = f2b(f.w);
      }
    }
    __syncthreads();
    #pragma unroll
    for (int ks = 0; ks < 2; ++ks) {
      bf16x8 af[4], bfr[4];
      #pragma unroll
      for (int i = 0; i < 4; ++i)
        af[i] = *(const bf16x8*)&As[(wr * 64 + i * 16 + l15) * 72 + ks * 32 + l4 * 8];
      #pragma unroll
      for (int i = 0; i < 4; ++i)
        bfr[i] = *(const bf16x8*)&Bs[(wc * 64 + i * 16 + l15) * 72 + ks * 32 + l4 * 8];
      #pragma unroll
      for (int mi = 0; mi < 4; ++mi)
        #pragma unroll
        for (int ni = 0; ni < 4; ++ni)
          acc[mi][ni] = __builtin_amdgcn_mfma_f32_16x16x32_bf16(
              af[mi], bfr[ni], acc[mi][ni], 0, 0, 0);
    }
    __syncthreads();
  }
  #pragma unroll
  for (int mi = 0; mi < 4; ++mi) {
    #pragma unroll
    for (int r = 0; r < 4; ++r) {
      const int grow = row0 + wr * 64 + mi * 16 + l4 * 4 + r;
      if (grow < MROWS) {
        const int bb = grow / NTOK, n = grow - bb * NTOK;
        #pragma unroll
        for (int ni = 0; ni < 4; ++ni) {
          const int gc = col0 + wc * 64 + ni * 16 + l15;
          const int which = gc >> 9;
          const int col = gc & 511;
          const int hh = col >> 6, d = col & 63;
          const size_t off = (size_t)((bb * NH + hh) * NTOK + n) * DH + d;
          const float vv = acc[mi][ni][r];
          if (which == 0)      qb[off] = f2b(vv * QSCALE);
          else if (which == 1) kb[off] = f2b(vv);
          else                 vb[off] = f2b(vv);
        }
      }
    }
  }
}

// ============ MFMA GEMM 2: out = attn(bf16) @ W_out -> fp32 =================
__global__ __launch_bounds__(256) void k_out(
    const unsigned short* __restrict__ a,   // bf16 [MROWS][512]
    const float* __restrict__ w,            // fp32 [512][512]
    float* __restrict__ out)                // fp32 [MROWS][512]
{
  __shared__ alignas(16) unsigned short As[128 * 72];
  __shared__ alignas(16) unsigned short Bs[128 * 72];
  const int bm = blockIdx.x, bn = blockIdx.y;
  const int tid = threadIdx.x;
  const int lane = tid & 63, wid = tid >> 6;
  const int wr = wid >> 1, wc = wid & 1;
  const int row0 = bm * 128, col0 = bn * 128;
  const int l15 = lane & 15, l4 = lane >> 4;

  f32x4 acc[4][4];
  #pragma unroll
  for (int i = 0; i < 4; ++i)
    #pragma unroll
    for (int j = 0; j < 4; ++j) acc[i][j] = f32x4{0.f, 0.f, 0.f, 0.f};

  for (int kt = 0; kt < 512; kt += 64) {
    {
      const int r = tid >> 1, k0 = (tid & 1) * 32;
      const int gr = row0 + r;
      if (gr < MROWS) {
        const unsigned short* src = a + (size_t)gr * 512 + kt + k0;
        #pragma unroll
        for (int cch = 0; cch < 4; ++cch)
          *(uint4*)&As[r * 72 + k0 + cch * 8] = *(const uint4*)(src + cch * 8);
      } else {
        const uint4 z = {0, 0, 0, 0};
        #pragma unroll
        for (int cch = 0; cch < 4; ++cch) *(uint4*)&As[r * 72 + k0 + cch * 8] = z;
      }
    }
    {
      const int kk = tid >> 2, j0 = (tid & 3) * 32;
      const float* src = w + (size_t)(kt + kk) * 512 + col0 + j0;
      #pragma unroll
      for (int jc = 0; jc < 32; jc += 4) {
        const float4 f = *(const float4*)(src + jc);
        Bs[(j0 + jc + 0) * 72 + kk] = f2b(f.x);
        Bs[(j0 + jc + 1) * 72 + kk] = f2b(f.y);
        Bs[(j0 + jc + 2) * 72 + kk] = f2b(f.z);
        Bs[(j0 + jc + 3) * 72 + kk] = f2b(f.w);
      }
    }
    __syncthreads();
    #pragma unroll
    for (int ks = 0; ks < 2; ++ks) {
      bf16x8 af[4], bfr[4];
      #pragma unroll
      for (int i = 0; i < 4; ++i)
        af[i] = *(const bf16x8*)&As[(wr * 64 + i * 16 + l15) * 72 + ks * 32 + l4 * 8];
      #pragma unroll
      for (int i = 0; i < 4; ++i)
        bfr[i] = *(const bf16x8*)&Bs[(wc * 64 + i * 16 + l15) * 72 + ks * 32 + l4 * 8];
      #pragma unroll
      for (int mi = 0; mi < 4; ++mi)
        #pragma unroll
        for (int ni = 0; ni < 4; ++ni)
          acc[mi][ni] = __builtin_amdgcn_mfma_f32_16x16x32_bf16(
              af[mi], bfr[ni], acc[mi][ni], 0, 0, 0);
    }
    __syncthreads();
  }
  #pragma unroll
  for (int mi = 0; mi < 4; ++mi) {
    #pragma unroll
    for (int r = 0; r < 4; ++r) {
      const int grow = row0 + wr * 64 + mi * 16 + l4 * 4 + r;
      if (grow < MROWS) {
        #pragma unroll
        for (int ni = 0; ni < 4; ++ni) {
          const int gc = col0 + wc * 64 + ni * 16 + l15;
          out[(size_t)grow * 512 + gc] = acc[mi][ni][r];
        }
      }
    }
  }
}

// ---------------- cls-token softmax attention -------------------------------
__global__ __launch_bounds__(256) void k_cls(
    const unsigned short* __restrict__ qb, const unsigned short* __restrict__ kb,
    const unsigned short* __restrict__ vb, unsigned short* __restrict__ attnb)
{
  __shared__ float sim[NTOK];
  __shared__ float qv[DH];
  __shared__ float sred[4], sred2[4];
  __shared__ float pbuf[4][DH];
  const int bh = blockIdx.x, tid = threadIdx.x;
  const int wv = tid >> 6, dcl = tid & 63;
  const unsigned short* ks = kb + (size_t)bh * NTOK * DH;
  const unsigned short* vs = vb + (size_t)bh * NTOK * DH;
  if (tid < DH) qv[tid] = b2f(qb[(size_t)bh * NTOK * DH + tid]);
  __syncthreads();
  float lmax = -1e30f;
  for (int j = tid; j < NTOK; j += 256) {
    const unsigned short* kr = ks + (size_t)j * DH;
    float dot = 0.f;
    #pragma unroll
    for (int d0 = 0; d0 < DH; d0 += 8) {
      const bf16x8 kv = *(const bf16x8*)(kr + d0);
      #pragma unroll
      for (int j2 = 0; j2 < 8; ++j2) dot += qv[d0 + j2] * (float)kv[j2];
    }
    sim[j] = dot;
    lmax = fmaxf(lmax, dot);
  }
  #pragma unroll
  for (int off = 32; off; off >>= 1) lmax = fmaxf(lmax, __shfl_xor(lmax, off));
  if ((tid & 63) == 0) sred[wv] = lmax;
  __syncthreads();
  const float mx = fmaxf(fmaxf(sred[0], sred[1]), fmaxf(sred[2], sred[3]));
  float lsum = 0.f;
  for (int j = tid; j < NTOK; j += 256) {
    const float p = expf(sim[j] - mx);
    sim[j] = p;
    lsum += p;
  }
  #pragma unroll
  for (int off = 32; off; off >>= 1) lsum += __shfl_xor(lsum, off);
  __syncthreads();
  if ((tid & 63) == 0) sred2[wv] = lsum;
  __syncthreads();
  const float tot = sred2[0] + sred2[1] + sred2[2] + sred2[3];
  float accv = 0.f;
  for (int j = wv; j < NTOK; j += 4) accv += sim[j] * b2f(vs[(size_t)j * DH + dcl]);
  pbuf[wv][dcl] = accv;
  __syncthreads();
  if (tid < DH) {
    const float o = (pbuf[0][tid] + pbuf[1][tid] + pbuf[2][tid] + pbuf[3][tid]) / tot;
    const int bb = bh >> 3, hh = bh & 7;
    attnb[((size_t)bb * NTOK + 0) * 512 + hh * DH + tid] = f2b(o);
  }
}

// ---------------- MFMA global key-projection max (pad-72) -------------------
__global__ __launch_bounds__(256) void k_keymax(
    const unsigned short* __restrict__ kb, const float* __restrict__ proj,
    float* __restrict__ pmax)
{
  __shared__ alignas(16) unsigned short projL[MP * PK];
  __shared__ float red[4];
  const int blk = blockIdx.x, tid = threadIdx.x;
  const int lane = tid & 63, wave = tid >> 6;
  const int l15 = lane & 15, l4 = lane >> 4;
  const int mw0 = wave * 80;
  for (int idx = tid; idx < MP * 64; idx += 256) {
    const int m = idx >> 6, d = idx & 63;
    projL[m * PK + d] = (m < MF) ? f2b(proj[m * 64 + d]) : (unsigned short)0;
  }
  __syncthreads();
  const int row0 = blk * 64;
  bf16x8 bfrag[4][2];
  #pragma unroll
  for (int tf = 0; tf < 4; ++tf) {
    int gr = row0 + tf * 16 + l15;
    if (gr >= NROWS) gr = NROWS - 1;
    #pragma unroll
    for (int ks = 0; ks < 2; ++ks)
      bfrag[tf][ks] = *(const bf16x8*)(kb + (size_t)gr * 64 + ks * 32 + l4 * 8);
  }
  f32x4 acc[5][4];
  #pragma unroll
  for (int i = 0; i < 5; ++i)
    #pragma unroll
    for (int j = 0; j < 4; ++j) acc[i][j] = f32x4{0.f, 0.f, 0.f, 0.f};
  #pragma unroll
  for (int mf = 0; mf < 5; ++mf) {
    const bf16x8 a0 = *(const bf16x8*)&projL[(mw0 + mf * 16 + l15) * PK + l4 * 8];
    const bf16x8 a1 = *(const bf16x8*)&projL[(mw0 + mf * 16 + l15) * PK + 32 + l4 * 8];
    #pragma unroll
    for (int tf = 0; tf < 4; ++tf) {
      acc[mf][tf] = __builtin_amdgcn_mfma_f32_16x16x32_bf16(a0, bfrag[tf][0], acc[mf][tf], 0, 0, 0);
      acc[mf][tf] = __builtin_amdgcn_mfma_f32_16x16x32_bf16(a1, bfrag[tf][1], acc[mf][tf], 0, 0, 0);
    }
  }
  float lm = -3e38f;
  #pragma unroll
  for (int tf = 0; tf < 4; ++tf) {
    const bool colok = (row0 + tf * 16 + l15) < NROWS;
    #pragma unroll
    for (int mf = 0; mf < 5; ++mf)
      #pragma unroll
      for (int r = 0; r < 4; ++r) {
        const int m = mw0 + mf * 16 + l4 * 4 + r;
        if (colok && m < MF) lm = fmaxf(lm, DN * acc[mf][tf][r]);
      }
  }
  #pragma unroll
  for (int off = 32; off; off >>= 1) lm = fmaxf(lm, __shfl_xor(lm, off));
  if (lane == 0) red[wave] = lm;
  __syncthreads();
  if (tid == 0) pmax[blk] = fmaxf(fmaxf(red[0], red[1]), fmaxf(red[2], red[3]));
}

__global__ __launch_bounds__(256) void k_maxred(
    const float* __restrict__ pmax, float* __restrict__ gmax)
{
  __shared__ float sred[4];
  float v = -3e38f;
  for (int i = threadIdx.x; i < NMAXB; i += 256) v = fmaxf(v, pmax[i]);
  #pragma unroll
  for (int off = 32; off; off >>= 1) v = fmaxf(v, __shfl_xor(v, off));
  if ((threadIdx.x & 63) == 0) sred[threadIdx.x >> 6] = v;
  __syncthreads();
  if (threadIdx.x == 0)
    gmax[0] = fmaxf(fmaxf(sred[0], sred[1]), fmaxf(sred[2], sred[3]));
}

// ------- fused per-group, full-MFMA, 8 waves, padded LDS --------------------
// Waves 0..3 own 3 m-frags at M0=48w; waves 4..7 own 2 m-frags at 192+32(w-4).
// Stage 4: wave w -> t-frag (w&3), ks-half (w>>2); pair-reduce via LDS f32.
__global__ __launch_bounds__(512) void k_fused(
    const unsigned short* __restrict__ qb, const unsigned short* __restrict__ kb,
    const unsigned short* __restrict__ vb, const float* __restrict__ proj,
    const float* __restrict__ gmaxp, unsigned short* __restrict__ attnb)
{
  __shared__ alignas(16) unsigned short projL[MP * PK];   // 46.1 KB [m][d]
  __shared__ alignas(16) unsigned short kpqp[MP * PK];    // 46.1 KB: A KP_T[m][t]; B QP[t][m](PM) / f32 scratch
  __shared__ alignas(16) unsigned short ctxT[80 * PM];    // 52.5 KB [d][m]; head doubles as vT[80][PK]
  __shared__ float diag_l[64];
  __shared__ float rmax_l[8][64];

  const int g = blockIdx.x, bh = g >> 4, c = g & 15;
  const int bb = bh >> 3, hh = bh & 7;
  const int tid = threadIdx.x;
  const int lane = tid & 63, wave = tid >> 6;
  const int l15 = lane & 15, l4 = lane >> 4;
  const int nf = (wave < 4) ? 3 : 2;
  const int M0 = (wave < 4) ? wave * 48 : 192 + (wave - 4) * 32;
  const float gm = gmaxp[0];
  unsigned short* vT = ctxT;  // [80][PK] region during phase A

  for (int idx = tid; idx < MP * 64; idx += 512) {
    const int m = idx >> 6, d = idx & 63;
    projL[m * PK + d] = (m < MF) ? f2b(proj[m * 64 + d]) : (unsigned short)0;
  }

  const unsigned short* ksrc = kb + (size_t)bh * NTOK * 64;
  const unsigned short* vsrc = vb + (size_t)bh * NTOK * 64;
  const unsigned short* qsrc = qb + (size_t)bh * NTOK * 64;

  f32x4 ctxacc[3][5];
  #pragma unroll
  for (int i = 0; i < 3; ++i)
    #pragma unroll
    for (int j = 0; j < 5; ++j) ctxacc[i][j] = f32x4{0.f, 0.f, 0.f, 0.f};

  // =============== phase A: 4 key tiles (197 tokens) ===============
  for (int kt = 0; kt < 4; ++kt) {
    const int tc = (kt < 3) ? 64 : 5;
    __syncthreads();
    {  // stage vT: thread (t=tid&63, dblk=tid>>6) -> conflict-free col writes
      const int t = tid & 63, dblk = tid >> 6;
      const int n = kt * 64 + t;
      if (n < 197) {
        const int node = (n == 0) ? 0 : 1 + c * 196 + (n - 1);
        const ushort8 v = *(const ushort8*)(vsrc + (size_t)node * 64 + dblk * 8);
        #pragma unroll
        for (int j = 0; j < 8; ++j) vT[(dblk * 8 + j) * PK + t] = v[j];
      } else {
        #pragma unroll
        for (int j = 0; j < 8; ++j) vT[(dblk * 8 + j) * PK + t] = 0;
      }
      if (tid < 64) vT[64 * PK + tid] = (tid < tc) ? (unsigned short)0x3F80 : (unsigned short)0;
    }
    if (tid < 64) {  // diag from K rows
      const int n = kt * 64 + tid;
      const int nn = (n < 197) ? n : 0;
      const int node = (nn == 0) ? 0 : 1 + c * 196 + (nn - 1);
      const unsigned short* kr = ksrc + (size_t)node * 64;
      float s = 0.f;
      #pragma unroll
      for (int d0 = 0; d0 < 64; d0 += 8) {
        const bf16x8 v = *(const bf16x8*)(kr + d0);
        #pragma unroll
        for (int j = 0; j < 8; ++j) { const float f = (float)v[j]; s += f * f; }
      }
      diag_l[tid] = HDN2 * s;
    }
    __syncthreads();
    // stage 1: DD_T[m][t] = proj . K^T
    bf16x8 bfrag[4][2];
    #pragma unroll
    for (int tf = 0; tf < 4; ++tf) {
      const int n = kt * 64 + tf * 16 + l15;
      const int nn = (n < 197) ? n : 0;
      const int node = (nn == 0) ? 0 : 1 + c * 196 + (nn - 1);
      #pragma unroll
      for (int ks = 0; ks < 2; ++ks)
        bfrag[tf][ks] = *(const bf16x8*)(ksrc + (size_t)node * 64 + ks * 32 + l4 * 8);
    }
    f32x4 acc[3][4];
    #pragma unroll
    for (int i = 0; i < 3; ++i)
      #pragma unroll
      for (int j = 0; j < 4; ++j) acc[i][j] = f32x4{0.f, 0.f, 0.f, 0.f};
    #pragma unroll
    for (int mf = 0; mf < 3; ++mf) {
      if (mf < nf) {
        const bf16x8 a0 = *(const bf16x8*)&projL[(M0 + mf * 16 + l15) * PK + l4 * 8];
        const bf16x8 a1 = *(const bf16x8*)&projL[(M0 + mf * 16 + l15) * PK + 32 + l4 * 8];
        #pragma unroll
        for (int tf = 0; tf < 4; ++tf) {
          acc[mf][tf] = __builtin_amdgcn_mfma_f32_16x16x32_bf16(a0, bfrag[tf][0], acc[mf][tf], 0, 0, 0);
          acc[mf][tf] = __builtin_amdgcn_mfma_f32_16x16x32_bf16(a1, bfrag[tf][1], acc[mf][tf], 0, 0, 0);
        }
      }
    }
    // kp = f(dd) -> KP_T[m][t]
    #pragma unroll
    for (int mf = 0; mf < 3; ++mf) {
      if (mf < nf) {
        #pragma unroll
        for (int tf = 0; tf < 4; ++tf) {
          const int t = tf * 16 + l15;
          const int n = kt * 64 + t;
          #pragma unroll
          for (int r = 0; r < 4; ++r) {
            const int m = M0 + mf * 16 + l4 * 4 + r;
            float kp = 0.f;
            if (m < MF && n < 197)
              kp = RATIO * (expf(DN * acc[mf][tf][r] - diag_l[t] - gm) + EPSV);
            kpqp[m * PK + t] = f2b(kp);
          }
        }
      }
    }
    __syncthreads();
    // stage 2: ctx += KP_T . V'
    #pragma unroll
    for (int ks = 0; ks < 2; ++ks) {
      bf16x8 a2[3];
      #pragma unroll
      for (int mf = 0; mf < 3; ++mf)
        if (mf < nf)
          a2[mf] = *(const bf16x8*)&kpqp[(M0 + mf * 16 + l15) * PK + ks * 32 + l4 * 8];
      #pragma unroll
      for (int df = 0; df < 5; ++df) {
        const bf16x8 b2 = *(const bf16x8*)&vT[(df * 16 + l15) * PK + ks * 32 + l4 * 8];
        #pragma unroll
        for (int mf = 0; mf < 3; ++mf)
          if (mf < nf)
            ctxacc[mf][df] = __builtin_amdgcn_mfma_f32_16x16x32_bf16(a2[mf], b2, ctxacc[mf][df], 0, 0, 0);
      }
    }
  }
  // write CTX_T[d][m] (packed 8B writes; overwrites vT region after barrier)
  __syncthreads();
  #pragma unroll
  for (int mf = 0; mf < 3; ++mf) {
    if (mf < nf) {
      #pragma unroll
      for (int df = 0; df < 5; ++df) {
        const int d = df * 16 + l15;
        const int m = M0 + mf * 16 + l4 * 4;
        uint2 u;
        u.x = pk2(ctxacc[mf][df][0], ctxacc[mf][df][1]);
        u.y = pk2(ctxacc[mf][df][2], ctxacc[mf][df][3]);
        *(uint2*)&ctxT[d * PM + m] = u;
      }
    }
  }

  // =============== phase B: 4 query tiles (196 tokens) ===============
  const int tf4 = wave & 3, ksb = (wave >> 2) * 5;
  float* scr = (float*)kpqp;  // [64][80] f32 partial-OUT scratch (20.5 KB)
  for (int qt = 0; qt < 4; ++qt) {
    const int tcq = (qt < 3) ? 64 : 4;
    __syncthreads();
    if (tid < 64) {  // diag from Q rows
      const int n = qt * 64 + tid;
      const int nn = (n < 196) ? n : 0;
      const int node = 1 + c * 196 + nn;
      const unsigned short* qr = qsrc + (size_t)node * 64;
      float s = 0.f;
      #pragma unroll
      for (int d0 = 0; d0 < 64; d0 += 8) {
        const bf16x8 v = *(const bf16x8*)(qr + d0);
        #pragma unroll
        for (int j = 0; j < 8; ++j) { const float f = (float)v[j]; s += f * f; }
      }
      diag_l[tid] = HDN2 * s;
    }
    // stage 3: DD_T = proj . Q^T
    bf16x8 bfrag[4][2];
    #pragma unroll
    for (int tf = 0; tf < 4; ++tf) {
      const int n = qt * 64 + tf * 16 + l15;
      const int nn = (n < 196) ? n : 0;
      const int node = 1 + c * 196 + nn;
      #pragma unroll
      for (int ks = 0; ks < 2; ++ks)
        bfrag[tf][ks] = *(const bf16x8*)(qsrc + (size_t)node * 64 + ks * 32 + l4 * 8);
    }
    f32x4 acc[3][4];
    #pragma unroll
    for (int i = 0; i < 3; ++i)
      #pragma unroll
      for (int j = 0; j < 4; ++j) acc[i][j] = f32x4{0.f, 0.f, 0.f, 0.f};
    #pragma unroll
    for (int mf = 0; mf < 3; ++mf) {
      if (mf < nf) {
        const bf16x8 a0 = *(const bf16x8*)&projL[(M0 + mf * 16 + l15) * PK + l4 * 8];
        const bf16x8 a1 = *(const bf16x8*)&projL[(M0 + mf * 16 + l15) * PK + 32 + l4 * 8];
        #pragma unroll
        for (int tf = 0; tf < 4; ++tf) {
          acc[mf][tf] = __builtin_amdgcn_mfma_f32_16x16x32_bf16(a0, bfrag[tf][0], acc[mf][tf], 0, 0, 0);
          acc[mf][tf] = __builtin_amdgcn_mfma_f32_16x16x32_bf16(a1, bfrag[tf][1], acc[mf][tf], 0, 0, 0);
        }
      }
    }
    // per-token rowmax over wave's m-slice
    #pragma unroll
    for (int tf = 0; tf < 4; ++tf) {
      float v = -3e38f;
      #pragma unroll
      for (int mf = 0; mf < 3; ++mf)
        if (mf < nf)
          #pragma unroll
          for (int r = 0; r < 4; ++r) {
            const int m = M0 + mf * 16 + l4 * 4 + r;
            if (m < MF) v = fmaxf(v, DN * acc[mf][tf][r]);
          }
      v = fmaxf(v, __shfl_xor(v, 16));
      v = fmaxf(v, __shfl_xor(v, 32));
      if (l4 == 0) rmax_l[wave][tf * 16 + l15] = v;
    }
    __syncthreads();
    // qp = f(dd) -> QP[t][m] (packed 8B writes)
    #pragma unroll
    for (int tf = 0; tf < 4; ++tf) {
      const int t = tf * 16 + l15;
      const int tq = qt * 64 + t;
      float rm = fmaxf(fmaxf(rmax_l[0][t], rmax_l[1][t]), fmaxf(rmax_l[2][t], rmax_l[3][t]));
      rm = fmaxf(rm, fmaxf(fmaxf(rmax_l[4][t], rmax_l[5][t]), fmaxf(rmax_l[6][t], rmax_l[7][t])));
      const float dg = diag_l[t];
      #pragma unroll
      for (int mf = 0; mf < 3; ++mf) {
        if (mf < nf) {
          float e[4];
          #pragma unroll
          for (int r = 0; r < 4; ++r) {
            const int m = M0 + mf * 16 + l4 * 4 + r;
            e[r] = (m < MF && tq < 196)
                 ? RATIO * (expf(DN * acc[mf][tf][r] - dg - rm) + EPSV) : 0.f;
          }
          uint2 u; u.x = pk2(e[0], e[1]); u.y = pk2(e[2], e[3]);
          *(uint2*)&kpqp[t * PM + M0 + mf * 16 + l4 * 4] = u;
        }
      }
    }
    __syncthreads();
    // stage 4: OUT[t][d] partial over ks-half
    f32x4 oacc[5];
    #pragma unroll
    for (int i = 0; i < 5; ++i) oacc[i] = f32x4{0.f, 0.f, 0.f, 0.f};
    #pragma unroll
    for (int ki = 0; ki < 5; ++ki) {
      const int ks = ksb + ki;
      const bf16x8 a4 = *(const bf16x8*)&kpqp[(tf4 * 16 + l15) * PM + ks * 32 + l4 * 8];
      #pragma unroll
      for (int df = 0; df < 5; ++df) {
        const bf16x8 b4 = *(const bf16x8*)&ctxT[(df * 16 + l15) * PM + ks * 32 + l4 * 8];
        oacc[df] = __builtin_amdgcn_mfma_f32_16x16x32_bf16(a4, b4, oacc[df], 0, 0, 0);
      }
    }
    __syncthreads();
    if (wave >= 4) {  // write partial to scratch (aliases dead QP)
      #pragma unroll
      for (int df = 0; df < 5; ++df)
        #pragma unroll
        for (int r = 0; r < 4; ++r)
          scr[(tf4 * 16 + l4 * 4 + r) * 80 + df * 16 + l15] = oacc[df][r];
    }
    __syncthreads();
    if (wave < 4) {
      #pragma unroll
      for (int df = 0; df < 5; ++df)
        #pragma unroll
        for (int r = 0; r < 4; ++r)
          oacc[df][r] += scr[(tf4 * 16 + l4 * 4 + r) * 80 + df * 16 + l15];
      #pragma unroll
      for (int r = 0; r < 4; ++r) {
        const int tq = qt * 64 + tf4 * 16 + l4 * 4 + r;
        const float denom = __shfl(oacc[4][r], lane & 48);
        if (tq < 196) {
          const float dinv = 1.0f / denom;
          const int node = 1 + c * 196 + tq;
          unsigned short* orow = attnb + ((size_t)bb * NTOK + node) * 512 + hh * 64;
          #pragma unroll
          for (int df = 0; df < 4; ++df)
            orow[df * 16 + l15] = f2b(oacc[df][r] * dinv);
        }
      }
    }
  }
}

}  // namespace

extern "C" void kernel_launch(void* const* d_in, const int* in_sizes, int n_in,
                              void* d_out, int out_size, void* d_ws, size_t ws_size,
                              hipStream_t stream) {
  (void)in_sizes; (void)n_in; (void)out_size; (void)ws_size;
  const float* x    = (const float*)d_in[0];
  const float* wqkv = (const float*)d_in[1];
  const float* wout = (const float*)d_in[2];
  const float* proj = (const float*)d_in[3];
  float* out = (float*)d_out;

  const size_t QKV = (size_t)BH * NTOK * DH;  // 12,849,152 elements
  unsigned short* qb    = (unsigned short*)d_ws;
  unsigned short* kb    = qb + QKV;
  unsigned short* vb    = kb + QKV;
  unsigned short* attnb = vb + QKV;
  float* pmax = (float*)(attnb + QKV);
  float* gmax = pmax + NMAXB;

  const dim3 blk(256);
  k_qkv    <<<dim3(197, 12), blk, 0, stream>>>(x, wqkv, qb, kb, vb);
  k_cls    <<<dim3(BH),      blk, 0, stream>>>(qb, kb, vb, attnb);
  k_keymax <<<dim3(NMAXB),   blk, 0, stream>>>(kb, proj, pmax);
  k_maxred <<<dim3(1),       blk, 0, stream>>>(pmax, gmax);
  k_fused  <<<dim3(1024), dim3(512), 0, stream>>>(qb, kb, vb, proj, gmax, attnb);
  k_out    <<<dim3(197, 4),  blk, 0, stream>>>(attnb, wout, out);
}

// Round 6
// 725.381 us; speedup vs baseline: 8.0509x; 1.0528x over previous
//
#include <hip/hip_runtime.h>
#include <hip/hip_bf16.h>

namespace {

typedef __bf16 bf16x8 __attribute__((ext_vector_type(8)));
typedef float  f32x4  __attribute__((ext_vector_type(4)));
typedef unsigned short ushort8 __attribute__((ext_vector_type(8)));

constexpr int NTOK  = 3137;          // 1 + 16*196
constexpr int NH    = 8;
constexpr int DH    = 64;
constexpr int BH    = 64;            // BATCH*NH
constexpr int MROWS = 8 * NTOK;      // 25096
constexpr int NROWS = BH * NTOK;     // 200768 (rows of kb)
constexpr int MF    = 266;           // NB_FEATURES
constexpr int MP    = 320;           // padded m
constexpr int NMAXB = NROWS / 64;    // 3137 keymax blocks

constexpr float DN     = 0.35355339059327379f;  // 64^-0.25
constexpr float HDN2   = 0.0625f;               // 0.5 * 64^-0.5
constexpr float RATIO  = 0.0613139368f;         // 266^-0.5
constexpr float EPSV   = 1.0e-4f;
constexpr float QSCALE = 0.125f;                // 64^-0.5

// XOR swizzle (T2): spreads 8 consecutive rows across 8 distinct 16B slots.
// Valid for any c (flips bits 3..5 only); keeps 8-elem chunks contiguous.
__device__ __forceinline__ int swz64(int r, int c)  { return (r << 6) + (c ^ ((r & 7) << 3)); }
__device__ __forceinline__ int swz320(int r, int c) { return r * 320 + (c ^ ((r & 7) << 3)); }

__device__ __forceinline__ float b2f(unsigned short u) {
  union { unsigned int i; float f; } cv;
  cv.i = ((unsigned int)u) << 16;
  return cv.f;
}
__device__ __forceinline__ unsigned short f2b(float f) {
  __hip_bfloat16 h = __float2bfloat16(f);
  union { __hip_bfloat16 h; unsigned short u; } cv;
  cv.h = h;
  return cv.u;
}
__device__ __forceinline__ unsigned int pk2(float a, float b) {
  return (unsigned int)f2b(a) | ((unsigned int)f2b(b) << 16);
}

// ============ MFMA GEMM 1: qkv = x @ W_qkv, scatter bf16 q/k/v ==============
__global__ __launch_bounds__(256) void k_qkv(
    const float* __restrict__ x,   // [MROWS][512]
    const float* __restrict__ w,   // [512][1536]
    unsigned short* __restrict__ qb, unsigned short* __restrict__ kb,
    unsigned short* __restrict__ vb)
{
  __shared__ alignas(16) unsigned short As[128 * 64];  // [m][k] swizzled
  __shared__ alignas(16) unsigned short Bs[128 * 64];  // [n][k] swizzled
  const int bm = blockIdx.x, bn = blockIdx.y;
  const int tid = threadIdx.x;
  const int lane = tid & 63, wid = tid >> 6;
  const int wr = wid >> 1, wc = wid & 1;
  const int row0 = bm * 128, col0 = bn * 128;
  const int l15 = lane & 15, l4 = lane >> 4;

  f32x4 acc[4][4];
  #pragma unroll
  for (int i = 0; i < 4; ++i)
    #pragma unroll
    for (int j = 0; j < 4; ++j) acc[i][j] = f32x4{0.f, 0.f, 0.f, 0.f};

  for (int kt = 0; kt < 512; kt += 64) {
    {
      const int r = tid >> 1, k0 = (tid & 1) * 32;
      const int gr = row0 + r;
      if (gr < MROWS) {
        const float* src = x + (size_t)gr * 512 + kt + k0;
        #pragma unroll
        for (int cch = 0; cch < 4; ++cch) {
          const float4 f0 = *(const float4*)(src + cch * 8);
          const float4 f1 = *(const float4*)(src + cch * 8 + 4);
          uint4 u;
          u.x = pk2(f0.x, f0.y); u.y = pk2(f0.z, f0.w);
          u.z = pk2(f1.x, f1.y); u.w = pk2(f1.z, f1.w);
          *(uint4*)&As[swz64(r, k0 + cch * 8)] = u;
        }
      } else {
        const uint4 z = {0, 0, 0, 0};
        #pragma unroll
        for (int cch = 0; cch < 4; ++cch) *(uint4*)&As[swz64(r, k0 + cch * 8)] = z;
      }
    }
    {
      const int kk = tid >> 2, j0 = (tid & 3) * 32;
      const float* src = w + (size_t)(kt + kk) * 1536 + col0 + j0;
      #pragma unroll
      for (int jc = 0; jc < 32; jc += 4) {
        const float4 f = *(const float4*)(src + jc);
        Bs[swz64(j0 + jc + 0, kk)] = f2b(f.x);
        Bs[swz64(j0 + jc + 1, kk)] = f2b(f.y);
        Bs[swz64(j0 + jc + 2, kk)] = f2b(f.z);
        Bs[swz64(j0 + jc + 3, kk)] = f2b(f.w);
      }
    }
    __syncthreads();
    #pragma unroll
    for (int ks = 0; ks < 2; ++ks) {
      bf16x8 af[4], bfr[4];
      #pragma unroll
      for (int i = 0; i < 4; ++i)
        af[i] = *(const bf16x8*)&As[swz64(wr * 64 + i * 16 + l15, ks * 32 + l4 * 8)];
      #pragma unroll
      for (int i = 0; i < 4; ++i)
        bfr[i] = *(const bf16x8*)&Bs[swz64(wc * 64 + i * 16 + l15, ks * 32 + l4 * 8)];
      #pragma unroll
      for (int mi = 0; mi < 4; ++mi)
        #pragma unroll
        for (int ni = 0; ni < 4; ++ni)
          acc[mi][ni] = __builtin_amdgcn_mfma_f32_16x16x32_bf16(
              af[mi], bfr[ni], acc[mi][ni], 0, 0, 0);
    }
    __syncthreads();
  }
  #pragma unroll
  for (int mi = 0; mi < 4; ++mi) {
    #pragma unroll
    for (int r = 0; r < 4; ++r) {
      const int grow = row0 + wr * 64 + mi * 16 + l4 * 4 + r;
      if (grow < MROWS) {
        const int bb = grow / NTOK, n = grow - bb * NTOK;
        #pragma unroll
        for (int ni = 0; ni < 4; ++ni) {
          const int gc = col0 + wc * 64 + ni * 16 + l15;
          const int which = gc >> 9;
          const int col = gc & 511;
          const int hh = col >> 6, d = col & 63;
          const size_t off = (size_t)((bb * NH + hh) * NTOK + n) * DH + d;
          const float vv = acc[mi][ni][r];
          if (which == 0)      qb[off] = f2b(vv * QSCALE);
          else if (which == 1) kb[off] = f2b(vv);
          else                 vb[off] = f2b(vv);
        }
      }
    }
  }
}

// ============ MFMA GEMM 2: out = attn(bf16) @ W_out -> fp32 =================
__global__ __launch_bounds__(256) void k_out(
    const unsigned short* __restrict__ a,   // bf16 [MROWS][512]
    const float* __restrict__ w,            // fp32 [512][512]
    float* __restrict__ out)                // fp32 [MROWS][512]
{
  __shared__ alignas(16) unsigned short As[128 * 64];
  __shared__ alignas(16) unsigned short Bs[128 * 64];
  const int bm = blockIdx.x, bn = blockIdx.y;
  const int tid = threadIdx.x;
  const int lane = tid & 63, wid = tid >> 6;
  const int wr = wid >> 1, wc = wid & 1;
  const int row0 = bm * 128, col0 = bn * 128;
  const int l15 = lane & 15, l4 = lane >> 4;

  f32x4 acc[4][4];
  #pragma unroll
  for (int i = 0; i < 4; ++i)
    #pragma unroll
    for (int j = 0; j < 4; ++j) acc[i][j] = f32x4{0.f, 0.f, 0.f, 0.f};

  for (int kt = 0; kt < 512; kt += 64) {
    {
      const int r = tid >> 1, k0 = (tid & 1) * 32;
      const int gr = row0 + r;
      if (gr < MROWS) {
        const unsigned short* src = a + (size_t)gr * 512 + kt + k0;
        #pragma unroll
        for (int cch = 0; cch < 4; ++cch)
          *(uint4*)&As[swz64(r, k0 + cch * 8)] = *(const uint4*)(src + cch * 8);
      } else {
        const uint4 z = {0, 0, 0, 0};
        #pragma unroll
        for (int cch = 0; cch < 4; ++cch) *(uint4*)&As[swz64(r, k0 + cch * 8)] = z;
      }
    }
    {
      const int kk = tid >> 2, j0 = (tid & 3) * 32;
      const float* src = w + (size_t)(kt + kk) * 512 + col0 + j0;
      #pragma unroll
      for (int jc = 0; jc < 32; jc += 4) {
        const float4 f = *(const float4*)(src + jc);
        Bs[swz64(j0 + jc + 0, kk)] = f2b(f.x);
        Bs[swz64(j0 + jc + 1, kk)] = f2b(f.y);
        Bs[swz64(j0 + jc + 2, kk)] = f2b(f.z);
        Bs[swz64(j0 + jc + 3, kk)] = f2b(f.w);
      }
    }
    __syncthreads();
    #pragma unroll
    for (int ks = 0; ks < 2; ++ks) {
      bf16x8 af[4], bfr[4];
      #pragma unroll
      for (int i = 0; i < 4; ++i)
        af[i] = *(const bf16x8*)&As[swz64(wr * 64 + i * 16 + l15, ks * 32 + l4 * 8)];
      #pragma unroll
      for (int i = 0; i < 4; ++i)
        bfr[i] = *(const bf16x8*)&Bs[swz64(wc * 64 + i * 16 + l15, ks * 32 + l4 * 8)];
      #pragma unroll
      for (int mi = 0; mi < 4; ++mi)
        #pragma unroll
        for (int ni = 0; ni < 4; ++ni)
          acc[mi][ni] = __builtin_amdgcn_mfma_f32_16x16x32_bf16(
              af[mi], bfr[ni], acc[mi][ni], 0, 0, 0);
    }
    __syncthreads();
  }
  #pragma unroll
  for (int mi = 0; mi < 4; ++mi) {
    #pragma unroll
    for (int r = 0; r < 4; ++r) {
      const int grow = row0 + wr * 64 + mi * 16 + l4 * 4 + r;
      if (grow < MROWS) {
        #pragma unroll
        for (int ni = 0; ni < 4; ++ni) {
          const int gc = col0 + wc * 64 + ni * 16 + l15;
          out[(size_t)grow * 512 + gc] = acc[mi][ni][r];
        }
      }
    }
  }
}

// ---------------- cls-token softmax attention -------------------------------
__global__ __launch_bounds__(256) void k_cls(
    const unsigned short* __restrict__ qb, const unsigned short* __restrict__ kb,
    const unsigned short* __restrict__ vb, unsigned short* __restrict__ attnb)
{
  __shared__ float sim[NTOK];
  __shared__ float qv[DH];
  __shared__ float sred[4], sred2[4];
  __shared__ float pbuf[4][DH];
  const int bh = blockIdx.x, tid = threadIdx.x;
  const int wv = tid >> 6, dcl = tid & 63;
  const unsigned short* ks = kb + (size_t)bh * NTOK * DH;
  const unsigned short* vs = vb + (size_t)bh * NTOK * DH;
  if (tid < DH) qv[tid] = b2f(qb[(size_t)bh * NTOK * DH + tid]);
  __syncthreads();
  float lmax = -1e30f;
  for (int j = tid; j < NTOK; j += 256) {
    const unsigned short* kr = ks + (size_t)j * DH;
    float dot = 0.f;
    #pragma unroll
    for (int d0 = 0; d0 < DH; d0 += 8) {
      const bf16x8 kv = *(const bf16x8*)(kr + d0);
      #pragma unroll
      for (int j2 = 0; j2 < 8; ++j2) dot += qv[d0 + j2] * (float)kv[j2];
    }
    sim[j] = dot;
    lmax = fmaxf(lmax, dot);
  }
  #pragma unroll
  for (int off = 32; off; off >>= 1) lmax = fmaxf(lmax, __shfl_xor(lmax, off));
  if ((tid & 63) == 0) sred[wv] = lmax;
  __syncthreads();
  const float mx = fmaxf(fmaxf(sred[0], sred[1]), fmaxf(sred[2], sred[3]));
  float lsum = 0.f;
  for (int j = tid; j < NTOK; j += 256) {
    const float p = __expf(sim[j] - mx);
    sim[j] = p;
    lsum += p;
  }
  #pragma unroll
  for (int off = 32; off; off >>= 1) lsum += __shfl_xor(lsum, off);
  __syncthreads();
  if ((tid & 63) == 0) sred2[wv] = lsum;
  __syncthreads();
  const float tot = sred2[0] + sred2[1] + sred2[2] + sred2[3];
  float accv = 0.f;
  for (int j = wv; j < NTOK; j += 4) accv += sim[j] * b2f(vs[(size_t)j * DH + dcl]);
  pbuf[wv][dcl] = accv;
  __syncthreads();
  if (tid < DH) {
    const float o = (pbuf[0][tid] + pbuf[1][tid] + pbuf[2][tid] + pbuf[3][tid]) / tot;
    const int bb = bh >> 3, hh = bh & 7;
    attnb[((size_t)bb * NTOK + 0) * 512 + hh * DH + tid] = f2b(o);
  }
}

// ---------------- MFMA global key-projection max (swizzled) -----------------
__global__ __launch_bounds__(256) void k_keymax(
    const unsigned short* __restrict__ kb, const float* __restrict__ proj,
    float* __restrict__ pmax)
{
  __shared__ alignas(16) unsigned short projL[MP * 64];
  __shared__ float red[4];
  const int blk = blockIdx.x, tid = threadIdx.x;
  const int lane = tid & 63, wave = tid >> 6;
  const int l15 = lane & 15, l4 = lane >> 4;
  const int mw0 = wave * 80;
  for (int idx = tid; idx < MP * 64; idx += 256) {
    const int m = idx >> 6, d = idx & 63;
    projL[swz64(m, d)] = (m < MF) ? f2b(proj[m * 64 + d]) : (unsigned short)0;
  }
  __syncthreads();
  const int row0 = blk * 64;
  bf16x8 bfrag[4][2];
  #pragma unroll
  for (int tf = 0; tf < 4; ++tf) {
    int gr = row0 + tf * 16 + l15;
    if (gr >= NROWS) gr = NROWS - 1;
    #pragma unroll
    for (int ks = 0; ks < 2; ++ks)
      bfrag[tf][ks] = *(const bf16x8*)(kb + (size_t)gr * 64 + ks * 32 + l4 * 8);
  }
  f32x4 acc[5][4];
  #pragma unroll
  for (int i = 0; i < 5; ++i)
    #pragma unroll
    for (int j = 0; j < 4; ++j) acc[i][j] = f32x4{0.f, 0.f, 0.f, 0.f};
  #pragma unroll
  for (int mf = 0; mf < 5; ++mf) {
    const bf16x8 a0 = *(const bf16x8*)&projL[swz64(mw0 + mf * 16 + l15, l4 * 8)];
    const bf16x8 a1 = *(const bf16x8*)&projL[swz64(mw0 + mf * 16 + l15, 32 + l4 * 8)];
    #pragma unroll
    for (int tf = 0; tf < 4; ++tf) {
      acc[mf][tf] = __builtin_amdgcn_mfma_f32_16x16x32_bf16(a0, bfrag[tf][0], acc[mf][tf], 0, 0, 0);
      acc[mf][tf] = __builtin_amdgcn_mfma_f32_16x16x32_bf16(a1, bfrag[tf][1], acc[mf][tf], 0, 0, 0);
    }
  }
  float lm = -3e38f;
  #pragma unroll
  for (int tf = 0; tf < 4; ++tf) {
    const bool colok = (row0 + tf * 16 + l15) < NROWS;
    #pragma unroll
    for (int mf = 0; mf < 5; ++mf)
      #pragma unroll
      for (int r = 0; r < 4; ++r) {
        const int m = mw0 + mf * 16 + l4 * 4 + r;
        if (colok && m < MF) lm = fmaxf(lm, DN * acc[mf][tf][r]);
      }
  }
  #pragma unroll
  for (int off = 32; off; off >>= 1) lm = fmaxf(lm, __shfl_xor(lm, off));
  if (lane == 0) red[wave] = lm;
  __syncthreads();
  if (tid == 0) pmax[blk] = fmaxf(fmaxf(red[0], red[1]), fmaxf(red[2], red[3]));
}

__global__ __launch_bounds__(256) void k_maxred(
    const float* __restrict__ pmax, float* __restrict__ gmax)
{
  __shared__ float sred[4];
  float v = -3e38f;
  for (int i = threadIdx.x; i < NMAXB; i += 256) v = fmaxf(v, pmax[i]);
  #pragma unroll
  for (int off = 32; off; off >>= 1) v = fmaxf(v, __shfl_xor(v, off));
  if ((threadIdx.x & 63) == 0) sred[threadIdx.x >> 6] = v;
  __syncthreads();
  if (threadIdx.x == 0)
    gmax[0] = fmaxf(fmaxf(sred[0], sred[1]), fmaxf(sred[2], sred[3]));
}

// ------- fused per-group, full-MFMA, 8 waves, XOR-swizzled LDS --------------
__global__ __launch_bounds__(512) void k_fused(
    const unsigned short* __restrict__ qb, const unsigned short* __restrict__ kb,
    const unsigned short* __restrict__ vb, const float* __restrict__ proj,
    const float* __restrict__ gmaxp, unsigned short* __restrict__ attnb)
{
  __shared__ alignas(16) unsigned short projL[MP * 64];   // 40 KB [m][d] swz64
  __shared__ alignas(16) unsigned short kpqp[64 * MP];    // 40 KB: A KP_T[m][64] swz64; B QP[t][320] swz320; scr f32[64][81]
  __shared__ alignas(16) unsigned short ctxT[80 * MP];    // 50 KB [d][320] swz320; head = vT[80][64] swz64
  __shared__ float diag_l[64];
  __shared__ float rmax_l[8][64];

  const int g = blockIdx.x, bh = g >> 4, c = g & 15;
  const int bb = bh >> 3, hh = bh & 7;
  const int tid = threadIdx.x;
  const int lane = tid & 63, wave = tid >> 6;
  const int l15 = lane & 15, l4 = lane >> 4;
  const int nf = (wave < 4) ? 3 : 2;
  const int M0 = (wave < 4) ? wave * 48 : 192 + (wave - 4) * 32;
  const float gm = gmaxp[0];
  unsigned short* vT = ctxT;  // [80][64] swz64 region during phase A

  for (int idx = tid; idx < MP * 64; idx += 512) {
    const int m = idx >> 6, d = idx & 63;
    projL[swz64(m, d)] = (m < MF) ? f2b(proj[m * 64 + d]) : (unsigned short)0;
  }
  // zero vT rows 65..79 once (contiguous range covers swizzled rows exactly)
  for (int i = tid; i < 15 * 64; i += 512) vT[65 * 64 + i] = 0;

  const unsigned short* ksrc = kb + (size_t)bh * NTOK * 64;
  const unsigned short* vsrc = vb + (size_t)bh * NTOK * 64;
  const unsigned short* qsrc = qb + (size_t)bh * NTOK * 64;

  f32x4 ctxacc[3][5];
  #pragma unroll
  for (int i = 0; i < 3; ++i)
    #pragma unroll
    for (int j = 0; j < 5; ++j) ctxacc[i][j] = f32x4{0.f, 0.f, 0.f, 0.f};

  // =============== phase A: 4 key tiles (197 tokens) ===============
  for (int kt = 0; kt < 4; ++kt) {
    const int tc = (kt < 3) ? 64 : 5;
    __syncthreads();
    {  // stage vT (transposed V), swizzled scalar column writes
      const int t = tid & 63, dblk = tid >> 6;
      const int n = kt * 64 + t;
      if (n < 197) {
        const int node = (n == 0) ? 0 : 1 + c * 196 + (n - 1);
        const ushort8 v = *(const ushort8*)(vsrc + (size_t)node * 64 + dblk * 8);
        #pragma unroll
        for (int j = 0; j < 8; ++j) vT[swz64(dblk * 8 + j, t)] = v[j];
      } else {
        #pragma unroll
        for (int j = 0; j < 8; ++j) vT[swz64(dblk * 8 + j, t)] = 0;
      }
      if (tid < 64) vT[swz64(64, tid)] = (tid < tc) ? (unsigned short)0x3F80 : (unsigned short)0;
    }
    if (tid < 64) {  // diag from K rows
      const int n = kt * 64 + tid;
      const int nn = (n < 197) ? n : 0;
      const int node = (nn == 0) ? 0 : 1 + c * 196 + (nn - 1);
      const unsigned short* kr = ksrc + (size_t)node * 64;
      float s = 0.f;
      #pragma unroll
      for (int d0 = 0; d0 < 64; d0 += 8) {
        const bf16x8 v = *(const bf16x8*)(kr + d0);
        #pragma unroll
        for (int j = 0; j < 8; ++j) { const float f = (float)v[j]; s += f * f; }
      }
      diag_l[tid] = HDN2 * s;
    }
    __syncthreads();
    // stage 1: DD_T[m][t] = proj . K^T
    bf16x8 bfrag[4][2];
    #pragma unroll
    for (int tf = 0; tf < 4; ++tf) {
      const int n = kt * 64 + tf * 16 + l15;
      const int nn = (n < 197) ? n : 0;
      const int node = (nn == 0) ? 0 : 1 + c * 196 + (nn - 1);
      #pragma unroll
      for (int ks = 0; ks < 2; ++ks)
        bfrag[tf][ks] = *(const bf16x8*)(ksrc + (size_t)node * 64 + ks * 32 + l4 * 8);
    }
    f32x4 acc[3][4];
    #pragma unroll
    for (int i = 0; i < 3; ++i)
      #pragma unroll
      for (int j = 0; j < 4; ++j) acc[i][j] = f32x4{0.f, 0.f, 0.f, 0.f};
    #pragma unroll
    for (int mf = 0; mf < 3; ++mf) {
      if (mf < nf) {
        const bf16x8 a0 = *(const bf16x8*)&projL[swz64(M0 + mf * 16 + l15, l4 * 8)];
        const bf16x8 a1 = *(const bf16x8*)&projL[swz64(M0 + mf * 16 + l15, 32 + l4 * 8)];
        #pragma unroll
        for (int tf = 0; tf < 4; ++tf) {
          acc[mf][tf] = __builtin_amdgcn_mfma_f32_16x16x32_bf16(a0, bfrag[tf][0], acc[mf][tf], 0, 0, 0);
          acc[mf][tf] = __builtin_amdgcn_mfma_f32_16x16x32_bf16(a1, bfrag[tf][1], acc[mf][tf], 0, 0, 0);
        }
      }
    }
    // kp = f(dd) -> KP_T[m][t]
    #pragma unroll
    for (int mf = 0; mf < 3; ++mf) {
      if (mf < nf) {
        #pragma unroll
        for (int tf = 0; tf < 4; ++tf) {
          const int t = tf * 16 + l15;
          const int n = kt * 64 + t;
          #pragma unroll
          for (int r = 0; r < 4; ++r) {
            const int m = M0 + mf * 16 + l4 * 4 + r;
            float kp = 0.f;
            if (m < MF && n < 197)
              kp = RATIO * (__expf(DN * acc[mf][tf][r] - diag_l[t] - gm) + EPSV);
            kpqp[swz64(m, t)] = f2b(kp);
          }
        }
      }
    }
    __syncthreads();
    // stage 2: ctx += KP_T . V'
    #pragma unroll
    for (int ks = 0; ks < 2; ++ks) {
      bf16x8 a2[3];
      #pragma unroll
      for (int mf = 0; mf < 3; ++mf)
        if (mf < nf)
          a2[mf] = *(const bf16x8*)&kpqp[swz64(M0 + mf * 16 + l15, ks * 32 + l4 * 8)];
      #pragma unroll
      for (int df = 0; df < 5; ++df) {
        const bf16x8 b2 = *(const bf16x8*)&vT[swz64(df * 16 + l15, ks * 32 + l4 * 8)];
        #pragma unroll
        for (int mf = 0; mf < 3; ++mf)
          if (mf < nf)
            ctxacc[mf][df] = __builtin_amdgcn_mfma_f32_16x16x32_bf16(a2[mf], b2, ctxacc[mf][df], 0, 0, 0);
      }
    }
  }
  // write CTX_T[d][m] (8B packed, swizzled; overwrites vT region after barrier)
  __syncthreads();
  #pragma unroll
  for (int mf = 0; mf < 3; ++mf) {
    if (mf < nf) {
      #pragma unroll
      for (int df = 0; df < 5; ++df) {
        const int d = df * 16 + l15;
        const int m = M0 + mf * 16 + l4 * 4;
        uint2 u;
        u.x = pk2(ctxacc[mf][df][0], ctxacc[mf][df][1]);
        u.y = pk2(ctxacc[mf][df][2], ctxacc[mf][df][3]);
        *(uint2*)&ctxT[swz320(d, m)] = u;
      }
    }
  }

  // =============== phase B: 4 query tiles (196 tokens) ===============
  const int tf4 = wave & 3, ksb = (wave >> 2) * 5;
  float* scr = (float*)kpqp;  // [64][81] f32 partial-OUT scratch (odd stride)
  for (int qt = 0; qt < 4; ++qt) {
    __syncthreads();
    if (tid < 64) {  // diag from Q rows
      const int n = qt * 64 + tid;
      const int nn = (n < 196) ? n : 0;
      const int node = 1 + c * 196 + nn;
      const unsigned short* qr = qsrc + (size_t)node * 64;
      float s = 0.f;
      #pragma unroll
      for (int d0 = 0; d0 < 64; d0 += 8) {
        const bf16x8 v = *(const bf16x8*)(qr + d0);
        #pragma unroll
        for (int j = 0; j < 8; ++j) { const float f = (float)v[j]; s += f * f; }
      }
      diag_l[tid] = HDN2 * s;
    }
    // stage 3: DD_T = proj . Q^T
    bf16x8 bfrag[4][2];
    #pragma unroll
    for (int tf = 0; tf < 4; ++tf) {
      const int n = qt * 64 + tf * 16 + l15;
      const int nn = (n < 196) ? n : 0;
      const int node = 1 + c * 196 + nn;
      #pragma unroll
      for (int ks = 0; ks < 2; ++ks)
        bfrag[tf][ks] = *(const bf16x8*)(qsrc + (size_t)node * 64 + ks * 32 + l4 * 8);
    }
    f32x4 acc[3][4];
    #pragma unroll
    for (int i = 0; i < 3; ++i)
      #pragma unroll
      for (int j = 0; j < 4; ++j) acc[i][j] = f32x4{0.f, 0.f, 0.f, 0.f};
    #pragma unroll
    for (int mf = 0; mf < 3; ++mf) {
      if (mf < nf) {
        const bf16x8 a0 = *(const bf16x8*)&projL[swz64(M0 + mf * 16 + l15, l4 * 8)];
        const bf16x8 a1 = *(const bf16x8*)&projL[swz64(M0 + mf * 16 + l15, 32 + l4 * 8)];
        #pragma unroll
        for (int tf = 0; tf < 4; ++tf) {
          acc[mf][tf] = __builtin_amdgcn_mfma_f32_16x16x32_bf16(a0, bfrag[tf][0], acc[mf][tf], 0, 0, 0);
          acc[mf][tf] = __builtin_amdgcn_mfma_f32_16x16x32_bf16(a1, bfrag[tf][1], acc[mf][tf], 0, 0, 0);
        }
      }
    }
    // per-token rowmax over wave's m-slice
    #pragma unroll
    for (int tf = 0; tf < 4; ++tf) {
      float v = -3e38f;
      #pragma unroll
      for (int mf = 0; mf < 3; ++mf)
        if (mf < nf)
          #pragma unroll
          for (int r = 0; r < 4; ++r) {
            const int m = M0 + mf * 16 + l4 * 4 + r;
            if (m < MF) v = fmaxf(v, DN * acc[mf][tf][r]);
          }
      v = fmaxf(v, __shfl_xor(v, 16));
      v = fmaxf(v, __shfl_xor(v, 32));
      if (l4 == 0) rmax_l[wave][tf * 16 + l15] = v;
    }
    __syncthreads();
    // qp = f(dd) -> QP[t][m] (8B packed, swizzled)
    #pragma unroll
    for (int tf = 0; tf < 4; ++tf) {
      const int t = tf * 16 + l15;
      const int tq = qt * 64 + t;
      float rm = fmaxf(fmaxf(rmax_l[0][t], rmax_l[1][t]), fmaxf(rmax_l[2][t], rmax_l[3][t]));
      rm = fmaxf(rm, fmaxf(fmaxf(rmax_l[4][t], rmax_l[5][t]), fmaxf(rmax_l[6][t], rmax_l[7][t])));
      const float dg = diag_l[t];
      #pragma unroll
      for (int mf = 0; mf < 3; ++mf) {
        if (mf < nf) {
          float e[4];
          #pragma unroll
          for (int r = 0; r < 4; ++r) {
            const int m = M0 + mf * 16 + l4 * 4 + r;
            e[r] = (m < MF && tq < 196)
                 ? RATIO * (__expf(DN * acc[mf][tf][r] - dg - rm) + EPSV) : 0.f;
          }
          uint2 u; u.x = pk2(e[0], e[1]); u.y = pk2(e[2], e[3]);
          *(uint2*)&kpqp[swz320(t, M0 + mf * 16 + l4 * 4)] = u;
        }
      }
    }
    __syncthreads();
    // stage 4: OUT[t][d] partial over ks-half
    f32x4 oacc[5];
    #pragma unroll
    for (int i = 0; i < 5; ++i) oacc[i] = f32x4{0.f, 0.f, 0.f, 0.f};
    #pragma unroll
    for (int ki = 0; ki < 5; ++ki) {
      const int ks = ksb + ki;
      const bf16x8 a4 = *(const bf16x8*)&kpqp[swz320(tf4 * 16 + l15, ks * 32 + l4 * 8)];
      #pragma unroll
      for (int df = 0; df < 5; ++df) {
        const bf16x8 b4 = *(const bf16x8*)&ctxT[swz320(df * 16 + l15, ks * 32 + l4 * 8)];
        oacc[df] = __builtin_amdgcn_mfma_f32_16x16x32_bf16(a4, b4, oacc[df], 0, 0, 0);
      }
    }
    __syncthreads();
    if (wave >= 4) {  // write partial to scratch (aliases dead QP)
      #pragma unroll
      for (int df = 0; df < 5; ++df)
        #pragma unroll
        for (int r = 0; r < 4; ++r)
          scr[(tf4 * 16 + l4 * 4 + r) * 81 + df * 16 + l15] = oacc[df][r];
    }
    __syncthreads();
    if (wave < 4) {
      #pragma unroll
      for (int df = 0; df < 5; ++df)
        #pragma unroll
        for (int r = 0; r < 4; ++r)
          oacc[df][r] += scr[(tf4 * 16 + l4 * 4 + r) * 81 + df * 16 + l15];
      #pragma unroll
      for (int r = 0; r < 4; ++r) {
        const int tq = qt * 64 + tf4 * 16 + l4 * 4 + r;
        const float denom = __shfl(oacc[4][r], lane & 48);
        if (tq < 196) {
          const float dinv = 1.0f / denom;
          const int node = 1 + c * 196 + tq;
          unsigned short* orow = attnb + ((size_t)bb * NTOK + node) * 512 + hh * 64;
          #pragma unroll
          for (int df = 0; df < 4; ++df)
            orow[df * 16 + l15] = f2b(oacc[df][r] * dinv);
        }
      }
    }
  }
}

}  // namespace

extern "C" void kernel_launch(void* const* d_in, const int* in_sizes, int n_in,
                              void* d_out, int out_size, void* d_ws, size_t ws_size,
                              hipStream_t stream) {
  (void)in_sizes; (void)n_in; (void)out_size; (void)ws_size;
  const float* x    = (const float*)d_in[0];
  const float* wqkv = (const float*)d_in[1];
  const float* wout = (const float*)d_in[2];
  const float* proj = (const float*)d_in[3];
  float* out = (float*)d_out;

  const size_t QKV = (size_t)BH * NTOK * DH;  // 12,849,152 elements
  unsigned short* qb    = (unsigned short*)d_ws;
  unsigned short* kb    = qb + QKV;
  unsigned short* vb    = kb + QKV;
  unsigned short* attnb = vb + QKV;
  float* pmax = (float*)(attnb + QKV);
  float* gmax = pmax + NMAXB;

  const dim3 blk(256);
  k_qkv    <<<dim3(197, 12), blk, 0, stream>>>(x, wqkv, qb, kb, vb);
  k_cls    <<<dim3(BH),      blk, 0, stream>>>(qb, kb, vb, attnb);
  k_keymax <<<dim3(NMAXB),   blk, 0, stream>>>(kb, proj, pmax);
  k_maxred <<<dim3(1),       blk, 0, stream>>>(pmax, gmax);
  k_fused  <<<dim3(1024), dim3(512), 0, stream>>>(qb, kb, vb, proj, gmax, attnb);
  k_out    <<<dim3(197, 4),  blk, 0, stream>>>(attnb, wout, out);
}

// Round 8
// 515.492 us; speedup vs baseline: 11.3289x; 1.4072x over previous
//
#include <hip/hip_runtime.h>
#include <hip/hip_bf16.h>

namespace {

typedef __bf16 bf16x8 __attribute__((ext_vector_type(8)));
typedef float  f32x4  __attribute__((ext_vector_type(4)));
typedef unsigned short ushort8 __attribute__((ext_vector_type(8)));

constexpr int NTOK  = 3137;          // 1 + 16*196
constexpr int NH    = 8;
constexpr int DH    = 64;
constexpr int BH    = 64;            // BATCH*NH
constexpr int MROWS = 8 * NTOK;      // 25096
constexpr int NROWS = BH * NTOK;     // 200768 (rows of kb)
constexpr int MF    = 266;           // NB_FEATURES
constexpr int MPK   = 320;           // keymax padded m
constexpr int MP    = 320;           // fused padded m (20 frags; MUST be mult of 64 for swizzle)
constexpr int NMAXB = NROWS / 64;    // 3137 keymax blocks
constexpr int NCH   = 13;            // cls chunks of 256

constexpr float DN     = 0.35355339059327379f;  // 64^-0.25
constexpr float HDN2   = 0.0625f;               // 0.5 * 64^-0.5
constexpr float RATIO  = 0.0613139368f;         // 266^-0.5
constexpr float EPSV   = 1.0e-4f;
constexpr float QSCALE = 0.125f;                // 64^-0.5

// XOR swizzle (T2): bijection within each complete 64-col block.
// Row stride MUST be a multiple of 64 (round-7 lesson: 288 broke this).
__device__ __forceinline__ int swz64(int r, int c)  { return (r << 6) + (c ^ ((r & 7) << 3)); }
__device__ __forceinline__ int swz320(int r, int c) { return r * 320 + (c ^ ((r & 7) << 3)); }

__device__ __forceinline__ float b2f(unsigned short u) {
  union { unsigned int i; float f; } cv;
  cv.i = ((unsigned int)u) << 16;
  return cv.f;
}
__device__ __forceinline__ unsigned short f2b(float f) {
  __hip_bfloat16 h = __float2bfloat16(f);
  union { __hip_bfloat16 h; unsigned short u; } cv;
  cv.h = h;
  return cv.u;
}
__device__ __forceinline__ unsigned int pk2(float a, float b) {
  return (unsigned int)f2b(a) | ((unsigned int)f2b(b) << 16);
}

// ============ MFMA GEMM 1: qkv = x @ W_qkv, scatter bf16 q/k/v ==============
// grid (12, 197): consecutive blocks share the same row-tile -> x L2/L3 reuse.
__global__ __launch_bounds__(256) void k_qkv(
    const float* __restrict__ x,   // [MROWS][512]
    const float* __restrict__ w,   // [512][1536]
    unsigned short* __restrict__ qb, unsigned short* __restrict__ kb,
    unsigned short* __restrict__ vb)
{
  __shared__ alignas(16) unsigned short As[128 * 64];  // [m][k] swizzled
  __shared__ alignas(16) unsigned short Bs[128 * 64];  // [n][k] swizzled
  const int bn = blockIdx.x, bm = blockIdx.y;
  const int tid = threadIdx.x;
  const int lane = tid & 63, wid = tid >> 6;
  const int wr = wid >> 1, wc = wid & 1;
  const int row0 = bm * 128, col0 = bn * 128;
  const int l15 = lane & 15, l4 = lane >> 4;

  f32x4 acc[4][4];
  #pragma unroll
  for (int i = 0; i < 4; ++i)
    #pragma unroll
    for (int j = 0; j < 4; ++j) acc[i][j] = f32x4{0.f, 0.f, 0.f, 0.f};

  for (int kt = 0; kt < 512; kt += 64) {
    {
      const int r = tid >> 1, k0 = (tid & 1) * 32;
      const int gr = row0 + r;
      if (gr < MROWS) {
        const float* src = x + (size_t)gr * 512 + kt + k0;
        #pragma unroll
        for (int cch = 0; cch < 4; ++cch) {
          const float4 f0 = *(const float4*)(src + cch * 8);
          const float4 f1 = *(const float4*)(src + cch * 8 + 4);
          uint4 u;
          u.x = pk2(f0.x, f0.y); u.y = pk2(f0.z, f0.w);
          u.z = pk2(f1.x, f1.y); u.w = pk2(f1.z, f1.w);
          *(uint4*)&As[swz64(r, k0 + cch * 8)] = u;
        }
      } else {
        const uint4 z = {0, 0, 0, 0};
        #pragma unroll
        for (int cch = 0; cch < 4; ++cch) *(uint4*)&As[swz64(r, k0 + cch * 8)] = z;
      }
    }
    {
      const int kk = tid >> 2, j0 = (tid & 3) * 32;
      const float* src = w + (size_t)(kt + kk) * 1536 + col0 + j0;
      #pragma unroll
      for (int jc = 0; jc < 32; jc += 4) {
        const float4 f = *(const float4*)(src + jc);
        Bs[swz64(j0 + jc + 0, kk)] = f2b(f.x);
        Bs[swz64(j0 + jc + 1, kk)] = f2b(f.y);
        Bs[swz64(j0 + jc + 2, kk)] = f2b(f.z);
        Bs[swz64(j0 + jc + 3, kk)] = f2b(f.w);
      }
    }
    __syncthreads();
    #pragma unroll
    for (int ks = 0; ks < 2; ++ks) {
      bf16x8 af[4], bfr[4];
      #pragma unroll
      for (int i = 0; i < 4; ++i)
        af[i] = *(const bf16x8*)&As[swz64(wr * 64 + i * 16 + l15, ks * 32 + l4 * 8)];
      #pragma unroll
      for (int i = 0; i < 4; ++i)
        bfr[i] = *(const bf16x8*)&Bs[swz64(wc * 64 + i * 16 + l15, ks * 32 + l4 * 8)];
      #pragma unroll
      for (int mi = 0; mi < 4; ++mi)
        #pragma unroll
        for (int ni = 0; ni < 4; ++ni)
          acc[mi][ni] = __builtin_amdgcn_mfma_f32_16x16x32_bf16(
              af[mi], bfr[ni], acc[mi][ni], 0, 0, 0);
    }
    __syncthreads();
  }
  #pragma unroll
  for (int mi = 0; mi < 4; ++mi) {
    #pragma unroll
    for (int r = 0; r < 4; ++r) {
      const int grow = row0 + wr * 64 + mi * 16 + l4 * 4 + r;
      if (grow < MROWS) {
        const int bb = grow / NTOK, n = grow - bb * NTOK;
        #pragma unroll
        for (int ni = 0; ni < 4; ++ni) {
          const int gc = col0 + wc * 64 + ni * 16 + l15;
          const int which = gc >> 9;
          const int col = gc & 511;
          const int hh = col >> 6, d = col & 63;
          const size_t off = (size_t)((bb * NH + hh) * NTOK + n) * DH + d;
          const float vv = acc[mi][ni][r];
          if (which == 0)      qb[off] = f2b(vv * QSCALE);
          else if (which == 1) kb[off] = f2b(vv);
          else                 vb[off] = f2b(vv);
        }
      }
    }
  }
}

// ============ MFMA GEMM 2: out = attn(bf16) @ W_out -> fp32 =================
__global__ __launch_bounds__(256) void k_out(
    const unsigned short* __restrict__ a,   // bf16 [MROWS][512]
    const float* __restrict__ w,            // fp32 [512][512]
    float* __restrict__ out)                // fp32 [MROWS][512]
{
  __shared__ alignas(16) unsigned short As[128 * 64];
  __shared__ alignas(16) unsigned short Bs[128 * 64];
  const int bm = blockIdx.x, bn = blockIdx.y;
  const int tid = threadIdx.x;
  const int lane = tid & 63, wid = tid >> 6;
  const int wr = wid >> 1, wc = wid & 1;
  const int row0 = bm * 128, col0 = bn * 128;
  const int l15 = lane & 15, l4 = lane >> 4;

  f32x4 acc[4][4];
  #pragma unroll
  for (int i = 0; i < 4; ++i)
    #pragma unroll
    for (int j = 0; j < 4; ++j) acc[i][j] = f32x4{0.f, 0.f, 0.f, 0.f};

  for (int kt = 0; kt < 512; kt += 64) {
    {
      const int r = tid >> 1, k0 = (tid & 1) * 32;
      const int gr = row0 + r;
      if (gr < MROWS) {
        const unsigned short* src = a + (size_t)gr * 512 + kt + k0;
        #pragma unroll
        for (int cch = 0; cch < 4; ++cch)
          *(uint4*)&As[swz64(r, k0 + cch * 8)] = *(const uint4*)(src + cch * 8);
      } else {
        const uint4 z = {0, 0, 0, 0};
        #pragma unroll
        for (int cch = 0; cch < 4; ++cch) *(uint4*)&As[swz64(r, k0 + cch * 8)] = z;
      }
    }
    {
      const int kk = tid >> 2, j0 = (tid & 3) * 32;
      const float* src = w + (size_t)(kt + kk) * 512 + col0 + j0;
      #pragma unroll
      for (int jc = 0; jc < 32; jc += 4) {
        const float4 f = *(const float4*)(src + jc);
        Bs[swz64(j0 + jc + 0, kk)] = f2b(f.x);
        Bs[swz64(j0 + jc + 1, kk)] = f2b(f.y);
        Bs[swz64(j0 + jc + 2, kk)] = f2b(f.z);
        Bs[swz64(j0 + jc + 3, kk)] = f2b(f.w);
      }
    }
    __syncthreads();
    #pragma unroll
    for (int ks = 0; ks < 2; ++ks) {
      bf16x8 af[4], bfr[4];
      #pragma unroll
      for (int i = 0; i < 4; ++i)
        af[i] = *(const bf16x8*)&As[swz64(wr * 64 + i * 16 + l15, ks * 32 + l4 * 8)];
      #pragma unroll
      for (int i = 0; i < 4; ++i)
        bfr[i] = *(const bf16x8*)&Bs[swz64(wc * 64 + i * 16 + l15, ks * 32 + l4 * 8)];
      #pragma unroll
      for (int mi = 0; mi < 4; ++mi)
        #pragma unroll
        for (int ni = 0; ni < 4; ++ni)
          acc[mi][ni] = __builtin_amdgcn_mfma_f32_16x16x32_bf16(
              af[mi], bfr[ni], acc[mi][ni], 0, 0, 0);
    }
    __syncthreads();
  }
  #pragma unroll
  for (int mi = 0; mi < 4; ++mi) {
    #pragma unroll
    for (int r = 0; r < 4; ++r) {
      const int grow = row0 + wr * 64 + mi * 16 + l4 * 4 + r;
      if (grow < MROWS) {
        #pragma unroll
        for (int ni = 0; ni < 4; ++ni) {
          const int gc = col0 + wc * 64 + ni * 16 + l15;
          out[(size_t)grow * 512 + gc] = acc[mi][ni][r];
        }
      }
    }
  }
}

// ---------------- cls attention, parallel 3-stage ---------------------------
__global__ __launch_bounds__(256) void k_cls1(
    const unsigned short* __restrict__ qb, const unsigned short* __restrict__ kb,
    float* __restrict__ simb, float* __restrict__ cmax)
{
  __shared__ float qv[64];
  __shared__ float sred[4];
  const int bh = blockIdx.x, ch = blockIdx.y, tid = threadIdx.x;
  if (tid < 64) qv[tid] = b2f(qb[(size_t)bh * NTOK * 64 + tid]);
  __syncthreads();
  const int j = ch * 256 + tid;
  float dot = -3e38f;
  if (j < NTOK) {
    const unsigned short* kr = kb + (size_t)bh * NTOK * 64 + (size_t)j * 64;
    dot = 0.f;
    #pragma unroll
    for (int d0 = 0; d0 < 64; d0 += 8) {
      const bf16x8 kv = *(const bf16x8*)(kr + d0);
      #pragma unroll
      for (int j2 = 0; j2 < 8; ++j2) dot += qv[d0 + j2] * (float)kv[j2];
    }
    simb[bh * 3200 + j] = dot;
  }
  float lm = dot;
  #pragma unroll
  for (int off = 32; off; off >>= 1) lm = fmaxf(lm, __shfl_xor(lm, off));
  if ((tid & 63) == 0) sred[tid >> 6] = lm;
  __syncthreads();
  if (tid == 0)
    cmax[bh * NCH + ch] = fmaxf(fmaxf(sred[0], sred[1]), fmaxf(sred[2], sred[3]));
}

__global__ __launch_bounds__(256) void k_cls2(
    const unsigned short* __restrict__ vb, const float* __restrict__ simb,
    const float* __restrict__ cmax, float* __restrict__ pacc,
    float* __restrict__ psum)
{
  __shared__ float pa[4][64];
  __shared__ float pw[4];
  const int bh = blockIdx.x, ch = blockIdx.y, tid = threadIdx.x;
  const int wave = tid >> 6, d = tid & 63;
  float mx = -3e38f;
  #pragma unroll
  for (int i = 0; i < NCH; ++i) mx = fmaxf(mx, cmax[bh * NCH + i]);
  float acc = 0.f, ps = 0.f;
  const int j0 = ch * 256 + wave * 64;
  for (int i = 0; i < 64; ++i) {
    const int j = j0 + i;
    if (j < NTOK) {
      const float p = __expf(simb[bh * 3200 + j] - mx);
      acc += p * b2f(vb[(size_t)bh * NTOK * 64 + (size_t)j * 64 + d]);
      ps += p;
    }
  }
  pa[wave][d] = acc;
  if (d == 0) pw[wave] = ps;
  __syncthreads();
  if (tid < 64)
    pacc[((size_t)bh * NCH + ch) * 64 + tid] = pa[0][tid] + pa[1][tid] + pa[2][tid] + pa[3][tid];
  if (tid == 0)
    psum[bh * NCH + ch] = pw[0] + pw[1] + pw[2] + pw[3];
}

__global__ __launch_bounds__(64) void k_cls3(
    const float* __restrict__ pacc, const float* __restrict__ psum,
    unsigned short* __restrict__ attnb)
{
  const int bh = blockIdx.x, d = threadIdx.x;
  float a = 0.f, s = 0.f;
  #pragma unroll
  for (int ch = 0; ch < NCH; ++ch) {
    a += pacc[((size_t)bh * NCH + ch) * 64 + d];
    s += psum[bh * NCH + ch];
  }
  const int bb = bh >> 3, hh = bh & 7;
  attnb[((size_t)bb * NTOK + 0) * 512 + hh * 64 + d] = f2b(a / s);
}

// ---------------- MFMA global key-projection max (swizzled) -----------------
__global__ __launch_bounds__(256) void k_keymax(
    const unsigned short* __restrict__ kb, const float* __restrict__ proj,
    float* __restrict__ pmax)
{
  __shared__ alignas(16) unsigned short projL[MPK * 64];
  __shared__ float red[4];
  const int blk = blockIdx.x, tid = threadIdx.x;
  const int lane = tid & 63, wave = tid >> 6;
  const int l15 = lane & 15, l4 = lane >> 4;
  const int mw0 = wave * 80;
  for (int idx = tid; idx < MPK * 64; idx += 256) {
    const int m = idx >> 6, d = idx & 63;
    projL[swz64(m, d)] = (m < MF) ? f2b(proj[m * 64 + d]) : (unsigned short)0;
  }
  __syncthreads();
  const int row0 = blk * 64;
  bf16x8 bfrag[4][2];
  #pragma unroll
  for (int tf = 0; tf < 4; ++tf) {
    int gr = row0 + tf * 16 + l15;
    if (gr >= NROWS) gr = NROWS - 1;
    #pragma unroll
    for (int ks = 0; ks < 2; ++ks)
      bfrag[tf][ks] = *(const bf16x8*)(kb + (size_t)gr * 64 + ks * 32 + l4 * 8);
  }
  f32x4 acc[5][4];
  #pragma unroll
  for (int i = 0; i < 5; ++i)
    #pragma unroll
    for (int j = 0; j < 4; ++j) acc[i][j] = f32x4{0.f, 0.f, 0.f, 0.f};
  #pragma unroll
  for (int mf = 0; mf < 5; ++mf) {
    const bf16x8 a0 = *(const bf16x8*)&projL[swz64(mw0 + mf * 16 + l15, l4 * 8)];
    const bf16x8 a1 = *(const bf16x8*)&projL[swz64(mw0 + mf * 16 + l15, 32 + l4 * 8)];
    #pragma unroll
    for (int tf = 0; tf < 4; ++tf) {
      acc[mf][tf] = __builtin_amdgcn_mfma_f32_16x16x32_bf16(a0, bfrag[tf][0], acc[mf][tf], 0, 0, 0);
      acc[mf][tf] = __builtin_amdgcn_mfma_f32_16x16x32_bf16(a1, bfrag[tf][1], acc[mf][tf], 0, 0, 0);
    }
  }
  float lm = -3e38f;
  #pragma unroll
  for (int tf = 0; tf < 4; ++tf) {
    const bool colok = (row0 + tf * 16 + l15) < NROWS;
    #pragma unroll
    for (int mf = 0; mf < 5; ++mf)
      #pragma unroll
      for (int r = 0; r < 4; ++r) {
        const int m = mw0 + mf * 16 + l4 * 4 + r;
        if (colok && m < MF) lm = fmaxf(lm, DN * acc[mf][tf][r]);
      }
  }
  #pragma unroll
  for (int off = 32; off; off >>= 1) lm = fmaxf(lm, __shfl_xor(lm, off));
  if (lane == 0) red[wave] = lm;
  __syncthreads();
  if (tid == 0) pmax[blk] = fmaxf(fmaxf(red[0], red[1]), fmaxf(red[2], red[3]));
}

__global__ __launch_bounds__(256) void k_maxred(
    const float* __restrict__ pmax, float* __restrict__ gmax)
{
  __shared__ float sred[4];
  float v = -3e38f;
  for (int i = threadIdx.x; i < NMAXB; i += 256) v = fmaxf(v, pmax[i]);
  #pragma unroll
  for (int off = 32; off; off >>= 1) v = fmaxf(v, __shfl_xor(v, off));
  if ((threadIdx.x & 63) == 0) sred[threadIdx.x >> 6] = v;
  __syncthreads();
  if (threadIdx.x == 0)
    gmax[0] = fmaxf(fmaxf(sred[0], sred[1]), fmaxf(sred[2], sred[3]));
}

// ------- fused per-group: proj in regs, ksum denominator, MP=320 ------------
// 20 m-frags: waves 0-3 own 3 (M0=48w), waves 4-7 own 2 (M0=192+32(w-4)).
__global__ __launch_bounds__(512) void k_fused(
    const unsigned short* __restrict__ qb, const unsigned short* __restrict__ kb,
    const unsigned short* __restrict__ vb, const float* __restrict__ proj,
    const float* __restrict__ gmaxp, unsigned short* __restrict__ attnb)
{
  __shared__ alignas(16) unsigned short kpqp[64 * MP];   // 40 KB: A KP_T[m][64] swz64; B QP[t][320] swz320; scr f32[64][68]
  __shared__ alignas(16) unsigned short ctxT[64 * MP];   // 40 KB: B ctx[d][320] swz320; head = vT[64][64] swz64
  __shared__ float diag_l[64];
  __shared__ float rmax_l[8][64];
  __shared__ float dnm_l[8][64];

  const int g = blockIdx.x, bh = g >> 4, c = g & 15;
  const int bb = bh >> 3, hh = bh & 7;
  const int tid = threadIdx.x;
  const int lane = tid & 63, wave = tid >> 6;
  const int l15 = lane & 15, l4 = lane >> 4;
  const int nf = (wave < 4) ? 3 : 2;
  const int M0 = (wave < 4) ? wave * 48 : 192 + (wave - 4) * 32;
  const float gm = gmaxp[0];
  unsigned short* vT = ctxT;  // [64][64] swz64 region during phase A

  // proj fragments in registers (wave reads only its own m-slice)
  bf16x8 pfr[3][2];
  #pragma unroll
  for (int mf = 0; mf < 3; ++mf) {
    #pragma unroll
    for (int ks = 0; ks < 2; ++ks) {
      const int m = M0 + mf * 16 + l15;
      union { bf16x8 v; ushort8 u; } cv;
      if (mf < nf && m < MF) {
        const float* src = proj + (size_t)m * 64 + ks * 32 + l4 * 8;
        const float4 f0 = *(const float4*)src;
        const float4 f1 = *(const float4*)(src + 4);
        cv.u[0] = f2b(f0.x); cv.u[1] = f2b(f0.y); cv.u[2] = f2b(f0.z); cv.u[3] = f2b(f0.w);
        cv.u[4] = f2b(f1.x); cv.u[5] = f2b(f1.y); cv.u[6] = f2b(f1.z); cv.u[7] = f2b(f1.w);
      } else {
        cv.u = ushort8{0, 0, 0, 0, 0, 0, 0, 0};
      }
      pfr[mf][ks] = cv.v;
    }
  }

  const unsigned short* ksrc = kb + (size_t)bh * NTOK * 64;
  const unsigned short* vsrc = vb + (size_t)bh * NTOK * 64;
  const unsigned short* qsrc = qb + (size_t)bh * NTOK * 64;

  f32x4 ctxacc[3][4];
  #pragma unroll
  for (int i = 0; i < 3; ++i)
    #pragma unroll
    for (int j = 0; j < 4; ++j) ctxacc[i][j] = f32x4{0.f, 0.f, 0.f, 0.f};
  float ksump[3][4];
  #pragma unroll
  for (int i = 0; i < 3; ++i)
    #pragma unroll
    for (int j = 0; j < 4; ++j) ksump[i][j] = 0.f;

  // =============== phase A: 4 key tiles (197 tokens) ===============
  for (int kt = 0; kt < 4; ++kt) {
    __syncthreads();
    {  // stage vT (transposed V), swizzled column writes
      const int t = tid & 63, dblk = (tid >> 6) & 7;
      const int n = kt * 64 + t;
      if (n < 197) {
        const int node = (n == 0) ? 0 : 1 + c * 196 + (n - 1);
        const ushort8 v = *(const ushort8*)(vsrc + (size_t)node * 64 + dblk * 8);
        #pragma unroll
        for (int j = 0; j < 8; ++j) vT[swz64(dblk * 8 + j, t)] = v[j];
      } else {
        #pragma unroll
        for (int j = 0; j < 8; ++j) vT[swz64(dblk * 8 + j, t)] = 0;
      }
    }
    if (tid < 64) {  // diag from K rows
      const int n = kt * 64 + tid;
      const int nn = (n < 197) ? n : 0;
      const int node = (nn == 0) ? 0 : 1 + c * 196 + (nn - 1);
      const unsigned short* kr = ksrc + (size_t)node * 64;
      float s = 0.f;
      #pragma unroll
      for (int d0 = 0; d0 < 64; d0 += 8) {
        const bf16x8 v = *(const bf16x8*)(kr + d0);
        #pragma unroll
        for (int j = 0; j < 8; ++j) { const float f = (float)v[j]; s += f * f; }
      }
      diag_l[tid] = HDN2 * s;
    }
    __syncthreads();
    // stage 1 (streamed per tf): DD_T[m][t] -> kp -> LDS, ksum partial
    #pragma unroll
    for (int tf = 0; tf < 4; ++tf) {
      const int n = kt * 64 + tf * 16 + l15;
      const int nn = (n < 197) ? n : 0;
      const int node = (nn == 0) ? 0 : 1 + c * 196 + (nn - 1);
      bf16x8 b0 = *(const bf16x8*)(ksrc + (size_t)node * 64 + l4 * 8);
      bf16x8 b1 = *(const bf16x8*)(ksrc + (size_t)node * 64 + 32 + l4 * 8);
      f32x4 a1[3];
      #pragma unroll
      for (int mf = 0; mf < 3; ++mf) {
        a1[mf] = f32x4{0.f, 0.f, 0.f, 0.f};
        if (mf < nf) {
          a1[mf] = __builtin_amdgcn_mfma_f32_16x16x32_bf16(pfr[mf][0], b0, a1[mf], 0, 0, 0);
          a1[mf] = __builtin_amdgcn_mfma_f32_16x16x32_bf16(pfr[mf][1], b1, a1[mf], 0, 0, 0);
        }
      }
      const int t = tf * 16 + l15;
      const int nv = kt * 64 + t;
      const float dg = diag_l[t];
      #pragma unroll
      for (int mf = 0; mf < 3; ++mf) {
        if (mf < nf) {
          #pragma unroll
          for (int r = 0; r < 4; ++r) {
            const int m = M0 + mf * 16 + l4 * 4 + r;
            float kp = 0.f;
            if (m < MF && nv < 197)
              kp = RATIO * (__expf(DN * a1[mf][r] - dg - gm) + EPSV);
            ksump[mf][r] += kp;
            kpqp[swz64(m, t)] = f2b(kp);
          }
        }
      }
    }
    // stage 2: ctx += KP_T . vT (wave reads only its own kpqp rows)
    #pragma unroll
    for (int ks = 0; ks < 2; ++ks) {
      bf16x8 a2[3];
      #pragma unroll
      for (int mf = 0; mf < 3; ++mf)
        if (mf < nf)
          a2[mf] = *(const bf16x8*)&kpqp[swz64(M0 + mf * 16 + l15, ks * 32 + l4 * 8)];
      #pragma unroll
      for (int df = 0; df < 4; ++df) {
        const bf16x8 b2 = *(const bf16x8*)&vT[swz64(df * 16 + l15, ks * 32 + l4 * 8)];
        #pragma unroll
        for (int mf = 0; mf < 3; ++mf)
          if (mf < nf)
            ctxacc[mf][df] = __builtin_amdgcn_mfma_f32_16x16x32_bf16(a2[mf], b2, ctxacc[mf][df], 0, 0, 0);
      }
    }
  }
  // ksum butterfly over l15 (lanes sharing l4 hold same m) -> total per lane
  float ksr[3][4];
  #pragma unroll
  for (int mf = 0; mf < 3; ++mf)
    #pragma unroll
    for (int r = 0; r < 4; ++r) {
      float v = ksump[mf][r];
      v += __shfl_xor(v, 1); v += __shfl_xor(v, 2);
      v += __shfl_xor(v, 4); v += __shfl_xor(v, 8);
      ksr[mf][r] = v;
    }
  // write CTX_T[d][m] (8B packed, swizzled; overwrites vT after barrier)
  __syncthreads();
  #pragma unroll
  for (int mf = 0; mf < 3; ++mf) {
    if (mf < nf) {
      #pragma unroll
      for (int df = 0; df < 4; ++df) {
        const int d = df * 16 + l15;
        const int m = M0 + mf * 16 + l4 * 4;
        uint2 u;
        u.x = pk2(ctxacc[mf][df][0], ctxacc[mf][df][1]);
        u.y = pk2(ctxacc[mf][df][2], ctxacc[mf][df][3]);
        *(uint2*)&ctxT[swz320(d, m)] = u;
      }
    }
  }

  // =============== phase B: 4 query tiles (196 tokens) ===============
  const int tf4 = wave & 3;
  const int ks0 = (wave >> 2) * 5;             // group0: ks 0..4, group1: 5..9
  float* scr = (float*)kpqp;                   // [64][68] f32 partial-OUT scratch
  for (int qt = 0; qt < 4; ++qt) {
    __syncthreads();
    if (tid < 64) {  // diag from Q rows
      const int n = qt * 64 + tid;
      const int nn = (n < 196) ? n : 0;
      const int node = 1 + c * 196 + nn;
      const unsigned short* qr = qsrc + (size_t)node * 64;
      float s = 0.f;
      #pragma unroll
      for (int d0 = 0; d0 < 64; d0 += 8) {
        const bf16x8 v = *(const bf16x8*)(qr + d0);
        #pragma unroll
        for (int j = 0; j < 8; ++j) { const float f = (float)v[j]; s += f * f; }
      }
      diag_l[tid] = HDN2 * s;
    }
    // stage 3: DD_T = proj . Q^T
    f32x4 acc[3][4];
    #pragma unroll
    for (int i = 0; i < 3; ++i)
      #pragma unroll
      for (int j = 0; j < 4; ++j) acc[i][j] = f32x4{0.f, 0.f, 0.f, 0.f};
    #pragma unroll
    for (int tf = 0; tf < 4; ++tf) {
      const int n = qt * 64 + tf * 16 + l15;
      const int nn = (n < 196) ? n : 0;
      const int node = 1 + c * 196 + nn;
      bf16x8 b0 = *(const bf16x8*)(qsrc + (size_t)node * 64 + l4 * 8);
      bf16x8 b1 = *(const bf16x8*)(qsrc + (size_t)node * 64 + 32 + l4 * 8);
      #pragma unroll
      for (int mf = 0; mf < 3; ++mf) {
        if (mf < nf) {
          acc[mf][tf] = __builtin_amdgcn_mfma_f32_16x16x32_bf16(pfr[mf][0], b0, acc[mf][tf], 0, 0, 0);
          acc[mf][tf] = __builtin_amdgcn_mfma_f32_16x16x32_bf16(pfr[mf][1], b1, acc[mf][tf], 0, 0, 0);
        }
      }
    }
    // per-token rowmax over wave's m-slice
    #pragma unroll
    for (int tf = 0; tf < 4; ++tf) {
      float v = -3e38f;
      #pragma unroll
      for (int mf = 0; mf < 3; ++mf)
        if (mf < nf)
          #pragma unroll
          for (int r = 0; r < 4; ++r) {
            const int m = M0 + mf * 16 + l4 * 4 + r;
            if (m < MF) v = fmaxf(v, DN * acc[mf][tf][r]);
          }
      v = fmaxf(v, __shfl_xor(v, 16));
      v = fmaxf(v, __shfl_xor(v, 32));
      if (l4 == 0) rmax_l[wave][tf * 16 + l15] = v;
    }
    __syncthreads();
    // qp = f(dd) -> QP[t][m]; denom partial via ksum
    #pragma unroll
    for (int tf = 0; tf < 4; ++tf) {
      const int t = tf * 16 + l15;
      const int tq = qt * 64 + t;
      float rm = fmaxf(fmaxf(rmax_l[0][t], rmax_l[1][t]), fmaxf(rmax_l[2][t], rmax_l[3][t]));
      rm = fmaxf(rm, fmaxf(fmaxf(rmax_l[4][t], rmax_l[5][t]), fmaxf(rmax_l[6][t], rmax_l[7][t])));
      const float dg = diag_l[t];
      float dpart = 0.f;
      #pragma unroll
      for (int mf = 0; mf < 3; ++mf) {
        if (mf < nf) {
          float e[4];
          #pragma unroll
          for (int r = 0; r < 4; ++r) {
            const int m = M0 + mf * 16 + l4 * 4 + r;
            e[r] = (m < MF && tq < 196)
                 ? RATIO * (__expf(DN * acc[mf][tf][r] - dg - rm) + EPSV) : 0.f;
            dpart += e[r] * ksr[mf][r];
          }
          uint2 u; u.x = pk2(e[0], e[1]); u.y = pk2(e[2], e[3]);
          *(uint2*)&kpqp[swz320(t, M0 + mf * 16 + l4 * 4)] = u;
        }
      }
      dpart += __shfl_xor(dpart, 16);
      dpart += __shfl_xor(dpart, 32);
      if (l4 == 0) dnm_l[wave][t] = dpart;
    }
    __syncthreads();
    // stage 4: OUT[t][d] partial over this wave-group's 5 ks chunks
    f32x4 oacc[4];
    #pragma unroll
    for (int i = 0; i < 4; ++i) oacc[i] = f32x4{0.f, 0.f, 0.f, 0.f};
    #pragma unroll
    for (int ki = 0; ki < 5; ++ki) {
      const int ks = ks0 + ki;
      const bf16x8 a4 = *(const bf16x8*)&kpqp[swz320(tf4 * 16 + l15, ks * 32 + l4 * 8)];
      #pragma unroll
      for (int df = 0; df < 4; ++df) {
        const bf16x8 b4 = *(const bf16x8*)&ctxT[swz320(df * 16 + l15, ks * 32 + l4 * 8)];
        oacc[df] = __builtin_amdgcn_mfma_f32_16x16x32_bf16(a4, b4, oacc[df], 0, 0, 0);
      }
    }
    __syncthreads();
    if (wave >= 4) {  // write partial to scratch (aliases dead QP)
      #pragma unroll
      for (int df = 0; df < 4; ++df)
        #pragma unroll
        for (int r = 0; r < 4; ++r)
          scr[(tf4 * 16 + l4 * 4 + r) * 68 + df * 16 + l15] = oacc[df][r];
    }
    __syncthreads();
    if (wave < 4) {
      #pragma unroll
      for (int df = 0; df < 4; ++df)
        #pragma unroll
        for (int r = 0; r < 4; ++r)
          oacc[df][r] += scr[(tf4 * 16 + l4 * 4 + r) * 68 + df * 16 + l15];
      #pragma unroll
      for (int r = 0; r < 4; ++r) {
        const int tl = tf4 * 16 + l4 * 4 + r;
        const int tq = qt * 64 + tl;
        if (tq < 196) {
          float denom = 0.f;
          #pragma unroll
          for (int w8 = 0; w8 < 8; ++w8) denom += dnm_l[w8][tl];
          const float dinv = 1.0f / denom;
          const int node = 1 + c * 196 + tq;
          unsigned short* orow = attnb + ((size_t)bb * NTOK + node) * 512 + hh * 64;
          #pragma unroll
          for (int df = 0; df < 4; ++df)
            orow[df * 16 + l15] = f2b(oacc[df][r] * dinv);
        }
      }
    }
  }
}

}  // namespace

extern "C" void kernel_launch(void* const* d_in, const int* in_sizes, int n_in,
                              void* d_out, int out_size, void* d_ws, size_t ws_size,
                              hipStream_t stream) {
  (void)in_sizes; (void)n_in; (void)out_size; (void)ws_size;
  const float* x    = (const float*)d_in[0];
  const float* wqkv = (const float*)d_in[1];
  const float* wout = (const float*)d_in[2];
  const float* proj = (const float*)d_in[3];
  float* out = (float*)d_out;

  const size_t QKV = (size_t)BH * NTOK * DH;  // 12,849,152 elements
  unsigned short* qb    = (unsigned short*)d_ws;
  unsigned short* kb    = qb + QKV;
  unsigned short* vb    = kb + QKV;
  unsigned short* attnb = vb + QKV;
  float* fbase = (float*)(attnb + QKV);       // 16B-aligned
  float* pmax = fbase;                        // 3137
  float* gmax = fbase + 4096;                 // 1
  float* simb = fbase + 8192;                 // 64*3200
  float* cmax = simb + 64 * 3200;             // 64*13
  float* pacc = cmax + 1024;                  // 64*13*64
  float* psum = pacc + 64 * NCH * 64;         // 64*13
  // total ws ~103.9 MB

  const dim3 blk(256);
  k_qkv    <<<dim3(12, 197),  blk, 0, stream>>>(x, wqkv, qb, kb, vb);
  k_cls1   <<<dim3(BH, NCH),  blk, 0, stream>>>(qb, kb, simb, cmax);
  k_cls2   <<<dim3(BH, NCH),  blk, 0, stream>>>(vb, simb, cmax, pacc, psum);
  k_cls3   <<<dim3(BH), dim3(64), 0, stream>>>(pacc, psum, attnb);
  k_keymax <<<dim3(NMAXB),    blk, 0, stream>>>(kb, proj, pmax);
  k_maxred <<<dim3(1),        blk, 0, stream>>>(pmax, gmax);
  k_fused  <<<dim3(1024), dim3(512), 0, stream>>>(qb, kb, vb, proj, gmax, attnb);
  k_out    <<<dim3(197, 4),   blk, 0, stream>>>(attnb, wout, out);
}